// Round 13
// baseline (370.557 us; speedup 1.0000x reference)
//
#include <hip/hip_runtime.h>
#include <cstddef>

#define N_NODES  50000
#define N_EDGES  800000
#define HDIM     128
#define SSUB     5000
#define GGRAPH   64
#define PB       3328           // part-A blocks (work-stealing, any >=8 works)
#define CHUNK    2048           // edges per work-steal grab (8 iters x 256)
#define NCHUNK   ((N_EDGES + CHUNK - 1) / CHUNK)   // 391
#define LDSW     136            // LDS row stride in ushorts (128 + 8 pad)

#define NB 196                  // node blocks ((50000+255)/256)
#define SB 20                   // subgraph blocks ((5000+255)/256)
#define WB 448                  // wconv blocks (7*16384/256)

typedef unsigned int uint;
typedef unsigned short ushort;
typedef __attribute__((ext_vector_type(8))) short bf16x8;
typedef __attribute__((ext_vector_type(16))) float f32x16;

// bf16 helpers (packed pair in a uint: low ushort = even feature, high = odd)
__device__ __forceinline__ float bflo(uint v) { return __uint_as_float(v << 16); }
__device__ __forceinline__ float bfhi(uint v) { return __uint_as_float(v & 0xffff0000u); }
__device__ __forceinline__ uint packbf(float lo, float hi) {
    uint a = __float_as_uint(lo), b = __float_as_uint(hi);
    a = (a + 0x7fff + ((a >> 16) & 1)) >> 16;          // RNE
    b = (b + 0x7fff + ((b >> 16) & 1)) & 0xffff0000u;  // RNE, keep high half
    return a | b;
}
__device__ __forceinline__ ushort bf16of(float f) {
    uint a = __float_as_uint(f);
    a = (a + 0x7fff + ((a >> 16) & 1)) >> 16;
    return (ushort)a;
}

// ---------------------------------------------------------------------------
// One-shot prep:
//  part A (PB blocks): XCD-local fixed-slot edge fill with WORK STEALING.
//    Each block reads its physical XCD id (HW_REG_XCC_ID, 0..7 — measured)
//    and drains 2048-edge chunks of partition x's full edge scan via an
//    atomic chunk counter. All deg atomics + csrc scatters for dst range
//    [x*6250, +6250) are issued from CUs on XCD x -> window truly local to
//    that XCD's L2 (atomics local, lines written back once).
//  part B (NB blocks): fixed-slot subgraph fill (cap 32; actual max ~25).
//  part D (SB blocks): fixed-slot subgraph->graph fill (cap 128; max ~110).
//  part C (WB blocks): weight convert -> bf16 transposed wt[m][n][k]=W[k][n].
// ---------------------------------------------------------------------------

__global__ __launch_bounds__(256) void k_prep(const int* __restrict__ src,
                                              const int* __restrict__ dst,
                                              int* __restrict__ deg,
                                              int* __restrict__ csrcF,
                                              int* __restrict__ chunkCtr,
                                              const int* __restrict__ n2s,
                                              int* __restrict__ sdeg,
                                              int* __restrict__ s2nF,
                                              const int* __restrict__ s2g,
                                              int* __restrict__ gcnt,
                                              int* __restrict__ g2sF,
                                              const float* __restrict__ W1b,
                                              const float* __restrict__ cWa,
                                              const float* __restrict__ cWb,
                                              ushort* __restrict__ wt) {
    int b = blockIdx.x, t = threadIdx.x;
    if (b < PB) {
        uint xcd;
        asm volatile("s_getreg_b32 %0, hwreg(HW_REG_XCC_ID, 0, 4)" : "=s"(xcd));
        xcd &= 7;
        const int lo = (int)xcd * 6250, hi = lo + 6250;
        for (;;) {
            int c;
            if (t == 0) c = atomicAdd(&chunkCtr[xcd], 1);
            c = __shfl(c, 0);                       // broadcast within wave 0...
            __shared__ int csh;
            if (t == 0) csh = c;
            __syncthreads();
            c = csh;
            if (c >= NCHUNK) break;
            int base = c * CHUNK;
#pragma unroll
            for (int i = 0; i < CHUNK / 256; ++i) {
                int e = base + i * 256 + t;
                if (e < N_EDGES) {
                    int d = dst[e];
                    if (d >= lo && d < hi) {
                        int pos = atomicAdd(&deg[d], 1);
                        if (pos < 64) csrcF[(d << 6) + pos] = src[e];
                    }
                }
            }
            __syncthreads();                        // csh reuse safety
        }
    } else if (b < PB + NB) {
        int i = (b - PB) * 256 + t;
        if (i < N_NODES) {
            int sg = n2s[i];
            int pos = atomicAdd(&sdeg[sg], 1);
            if (pos < 32) s2nF[(sg << 5) + pos] = i;
        }
    } else if (b < PB + NB + SB) {
        int i = (b - PB - NB) * 256 + t;
        if (i < SSUB) {
            int g = s2g[i];
            int pos = atomicAdd(&gcnt[g], 1);
            if (pos < 128) g2sF[(g << 7) + pos] = i;
        }
    } else {
        int gid = (b - PB - NB - SB) * 256 + t;    // 7*16384 total
        int m = gid >> 14, r = gid & 16383;
        int n = r >> 7, k = r & 127;
        const float* Wsrc = (m == 0) ? W1b
                          : (m <= 3) ? cWa + (size_t)(m - 1) * 16384
                                     : cWb + (size_t)(m - 4) * 16384;
        wt[gid] = bf16of(Wsrc[k * 128 + n]);
    }
}

// ---------------------------------------------------------------------------
// Conv 1, fully fused, parallel gather:
//  1a) 4 threads per node gather x (L2-hot) + shfl_xor reduce -> LDS sums
//  1b) wave-per-16-nodes applies W1a+b1a+relu -> 64x128 bf16 LDS tile
//   2) column-sliced 32x32x16 MFMA gemm (W1b^T slice reg-resident) -> hb
// ---------------------------------------------------------------------------

__global__ __launch_bounds__(256) void k_layer1(const float2* __restrict__ x,
                                                const int* __restrict__ deg,
                                                const int* __restrict__ csrcF,
                                                const float* __restrict__ W1a,
                                                const float* __restrict__ b1a,
                                                const ushort* __restrict__ WtA,
                                                const float* __restrict__ bA,
                                                ushort* __restrict__ hbout) {
    __shared__ ushort lds[64 * LDSW];   // 17.4 KB
    __shared__ float2 sums[64];
    const int tid = threadIdx.x, wave = tid >> 6, lane = tid & 63;
    const int nodeBase = blockIdx.x * 64;

    // ---- phase 1a: 4 threads per node gather + reduce ----
    {
        int nl = tid >> 2, sub = tid & 3;
        int gn = nodeBase + nl;
        float tx = 0.f, ty = 0.f;
        if (gn < N_NODES) {
            int e = deg[gn]; if (e > 64) e = 64;
            for (int k = sub; k < e; k += 4) {
                float2 v = x[csrcF[(gn << 6) + k]];
                tx += v.x; ty += v.y;
            }
        }
        tx += __shfl_xor(tx, 1); ty += __shfl_xor(ty, 1);
        tx += __shfl_xor(tx, 2); ty += __shfl_xor(ty, 2);
        if (sub == 0) {
            if (gn < N_NODES) {
                float2 sv = x[gn];
                sums[nl] = make_float2(tx + sv.x, ty + sv.y);
            } else {
                sums[nl] = make_float2(0.f, 0.f);
            }
        }
    }
    __syncthreads();

    // ---- phase 1b: lin1a + relu -> bf16 LDS tile ----
    {
        float2 wlo = ((const float2*)W1a)[lane];        // W1a[0][2l..2l+1]
        float2 whi = ((const float2*)W1a)[64 + lane];   // W1a[1][2l..2l+1]
        float2 bv  = ((const float2*)b1a)[lane];
        for (int n = wave * 16; n < wave * 16 + 16; ++n) {
            float2 ts = sums[n];
            float v0 = fmaf(ts.x, wlo.x, fmaf(ts.y, whi.x, bv.x));
            float v1 = fmaf(ts.x, wlo.y, fmaf(ts.y, whi.y, bv.y));
            *(uint*)(&lds[n * LDSW + 2 * lane]) = packbf(fmaxf(v0, 0.f), fmaxf(v1, 0.f));
        }
    }

    // ---- register-resident WtA slice ----
    const int l32 = lane & 31, hk = lane >> 5;
    const int colBase = wave * 32;
    bf16x8 wa[8];
#pragma unroll
    for (int kk = 0; kk < 8; ++kk)
        wa[kk] = *(const bf16x8*)(WtA + (size_t)(colBase + l32) * 128 + kk * 16 + hk * 8);
    const float biasA = bA[colBase + l32];
    __syncthreads();

    // ---- phase 2: column-sliced gemm, 2 m-tiles of 32 rows ----
    f32x16 acc[2];
#pragma unroll
    for (int m = 0; m < 2; ++m)
#pragma unroll
        for (int r = 0; r < 16; ++r) acc[m][r] = 0.f;
#pragma unroll
    for (int m = 0; m < 2; ++m) {
        const ushort* arow = lds + (m * 32 + l32) * LDSW + hk * 8;
#pragma unroll
        for (int kk = 0; kk < 8; ++kk) {
            bf16x8 a = *(const bf16x8*)(arow + kk * 16);
            acc[m] = __builtin_amdgcn_mfma_f32_32x32x16_bf16(a, wa[kk], acc[m], 0, 0, 0);
        }
    }

    // ---- epilogue: relu(acc + bA) -> bf16 global (masked rows) ----
#pragma unroll
    for (int m = 0; m < 2; ++m) {
#pragma unroll
        for (int r = 0; r < 16; ++r) {
            int rl = (r & 3) + 8 * (r >> 2) + 4 * hk;
            int row = nodeBase + m * 32 + rl;
            if (row < N_NODES)
                hbout[(size_t)row * 128 + colBase + l32] =
                    bf16of(fmaxf(acc[m][r] + biasA, 0.f));
        }
    }
}

// ---------------------------------------------------------------------------
// GIN aggregation, H=128, bf16 in/out: one wave per node, lane holds one uint
// (2 bf16 features), full 256 B row per gather, shfl broadcast of the
// (aligned) fixed-slot csrc list, up to 16 outstanding gathers.
// ---------------------------------------------------------------------------

__global__ __launch_bounds__(256) void k_aggr128_bf16(const uint* __restrict__ hb,
                                                      const int* __restrict__ deg,
                                                      const int* __restrict__ csrcF,
                                                      uint* __restrict__ out) {
    int node = blockIdx.x * 4 + (threadIdx.x >> 6);   // grid = N/4 exact
    int lane = threadIdx.x & 63;
    int cnt = deg[node]; if (cnt > 64) cnt = 64;
    uint sv = hb[(size_t)node * 64 + lane];
    float ax0 = bflo(sv), ay0 = bfhi(sv);
    float ax1 = 0.f, ay1 = 0.f, ax2 = 0.f, ay2 = 0.f, ax3 = 0.f, ay3 = 0.f;
    int idx = csrcF[(node << 6) + ((lane < cnt) ? lane : 0)];   // aligned 256 B load
    int j = 0;
    for (; j + 15 < cnt; j += 16) {                     // 16 outstanding gathers
        int s0 = __shfl(idx, j),      s1 = __shfl(idx, j + 1);
        int s2 = __shfl(idx, j + 2),  s3 = __shfl(idx, j + 3);
        int s4 = __shfl(idx, j + 4),  s5 = __shfl(idx, j + 5);
        int s6 = __shfl(idx, j + 6),  s7 = __shfl(idx, j + 7);
        int s8 = __shfl(idx, j + 8),  s9 = __shfl(idx, j + 9);
        int sa = __shfl(idx, j + 10), sb = __shfl(idx, j + 11);
        int sc = __shfl(idx, j + 12), sd = __shfl(idx, j + 13);
        int se = __shfl(idx, j + 14), sf = __shfl(idx, j + 15);
        uint v0 = hb[(size_t)s0 * 64 + lane];
        uint v1 = hb[(size_t)s1 * 64 + lane];
        uint v2 = hb[(size_t)s2 * 64 + lane];
        uint v3 = hb[(size_t)s3 * 64 + lane];
        uint v4 = hb[(size_t)s4 * 64 + lane];
        uint v5 = hb[(size_t)s5 * 64 + lane];
        uint v6 = hb[(size_t)s6 * 64 + lane];
        uint v7 = hb[(size_t)s7 * 64 + lane];
        uint v8 = hb[(size_t)s8 * 64 + lane];
        uint v9 = hb[(size_t)s9 * 64 + lane];
        uint va = hb[(size_t)sa * 64 + lane];
        uint vb = hb[(size_t)sb * 64 + lane];
        uint vc = hb[(size_t)sc * 64 + lane];
        uint vd = hb[(size_t)sd * 64 + lane];
        uint ve = hb[(size_t)se * 64 + lane];
        uint vf = hb[(size_t)sf * 64 + lane];
        ax0 += bflo(v0); ay0 += bfhi(v0);
        ax1 += bflo(v1); ay1 += bfhi(v1);
        ax2 += bflo(v2); ay2 += bfhi(v2);
        ax3 += bflo(v3); ay3 += bfhi(v3);
        ax0 += bflo(v4); ay0 += bfhi(v4);
        ax1 += bflo(v5); ay1 += bfhi(v5);
        ax2 += bflo(v6); ay2 += bfhi(v6);
        ax3 += bflo(v7); ay3 += bfhi(v7);
        ax0 += bflo(v8); ay0 += bfhi(v8);
        ax1 += bflo(v9); ay1 += bfhi(v9);
        ax2 += bflo(va); ay2 += bfhi(va);
        ax3 += bflo(vb); ay3 += bfhi(vb);
        ax0 += bflo(vc); ay0 += bfhi(vc);
        ax1 += bflo(vd); ay1 += bfhi(vd);
        ax2 += bflo(ve); ay2 += bfhi(ve);
        ax3 += bflo(vf); ay3 += bfhi(vf);
    }
    for (; j + 3 < cnt; j += 4) {
        int s0 = __shfl(idx, j),     s1 = __shfl(idx, j + 1);
        int s2 = __shfl(idx, j + 2), s3 = __shfl(idx, j + 3);
        uint v0 = hb[(size_t)s0 * 64 + lane];
        uint v1 = hb[(size_t)s1 * 64 + lane];
        uint v2 = hb[(size_t)s2 * 64 + lane];
        uint v3 = hb[(size_t)s3 * 64 + lane];
        ax0 += bflo(v0); ay0 += bfhi(v0);
        ax1 += bflo(v1); ay1 += bfhi(v1);
        ax2 += bflo(v2); ay2 += bfhi(v2);
        ax3 += bflo(v3); ay3 += bfhi(v3);
    }
    for (; j < cnt; ++j) {
        int sj = __shfl(idx, j);
        uint v = hb[(size_t)sj * 64 + lane];
        ax0 += bflo(v); ay0 += bfhi(v);
    }
    out[(size_t)node * 64 + lane] =
        packbf((ax0 + ax1) + (ax2 + ax3), (ay0 + ay1) + (ay2 + ay3));
}

// ---------------------------------------------------------------------------
// Fused GIN MLP — 64-row blocks, column-sliced 32x32x16 MFMA, B register-
// resident. Two LDS regions (input tile / intermediate tile) -> 2 barriers.
// ---------------------------------------------------------------------------

__global__ __launch_bounds__(256) void k_mlp(const ushort* __restrict__ A,
                                             const ushort* __restrict__ WtA,
                                             const float* __restrict__ bA,
                                             const ushort* __restrict__ WtB,
                                             const float* __restrict__ bB,
                                             ushort* __restrict__ C, int nrows) {
    __shared__ ushort ldsA[64 * LDSW];   // input tile (17.4 KB)
    __shared__ ushort ldsB[64 * LDSW];   // intermediate tile (17.4 KB)
    const int tid = threadIdx.x;
    const int wave = tid >> 6, lane = tid & 63;
    const int l32 = lane & 31, hk = lane >> 5;
    const int colBase = wave * 32;
    const int rowBase = blockIdx.x * 64;

    // ---- stage A tile into ldsA (thread t: row t>>2, 64 B quarter) ----
    {
        int r = tid >> 2;
        int qo = (tid & 3) * 32;                    // ushort offset (64 B quarter)
        const uint4* gp = (const uint4*)(A + (size_t)(rowBase + r) * 128 + qo);
        uint4* lp = (uint4*)(ldsA + r * LDSW + qo);
        bool valid = (rowBase + r) < nrows;
#pragma unroll
        for (int q = 0; q < 4; ++q) {
            uint4 v = valid ? gp[q] : (uint4){0u, 0u, 0u, 0u};
            lp[q] = v;
        }
    }

    // ---- register-resident Wt slices (loaded once, L2-hot) ----
    bf16x8 wa[8], wb[8];
#pragma unroll
    for (int kk = 0; kk < 8; ++kk) {
        wa[kk] = *(const bf16x8*)(WtA + (size_t)(colBase + l32) * 128 + kk * 16 + hk * 8);
        wb[kk] = *(const bf16x8*)(WtB + (size_t)(colBase + l32) * 128 + kk * 16 + hk * 8);
    }
    const float biasA = bA[colBase + l32];
    const float biasB = bB[colBase + l32];
    __syncthreads();

    // ---- gemm A (reads ldsA) ----
    f32x16 acc[2];
#pragma unroll
    for (int m = 0; m < 2; ++m)
#pragma unroll
        for (int r = 0; r < 16; ++r) acc[m][r] = 0.f;
#pragma unroll
    for (int m = 0; m < 2; ++m) {
        const ushort* arow = ldsA + (m * 32 + l32) * LDSW + hk * 8;
#pragma unroll
        for (int kk = 0; kk < 8; ++kk) {
            bf16x8 a = *(const bf16x8*)(arow + kk * 16);
            acc[m] = __builtin_amdgcn_mfma_f32_32x32x16_bf16(a, wa[kk], acc[m], 0, 0, 0);
        }
    }

    // ---- relu(acc + bA) -> ldsB (no barrier needed before writes) ----
#pragma unroll
    for (int m = 0; m < 2; ++m) {
#pragma unroll
        for (int r = 0; r < 16; ++r) {
            int rl = (r & 3) + 8 * (r >> 2) + 4 * hk;
            ldsB[(m * 32 + rl) * LDSW + colBase + l32] =
                bf16of(fmaxf(acc[m][r] + biasA, 0.f));
        }
    }
    __syncthreads();

    // ---- gemm B (reads ldsB) ----
#pragma unroll
    for (int m = 0; m < 2; ++m)
#pragma unroll
        for (int r = 0; r < 16; ++r) acc[m][r] = 0.f;
#pragma unroll
    for (int m = 0; m < 2; ++m) {
        const ushort* arow = ldsB + (m * 32 + l32) * LDSW + hk * 8;
#pragma unroll
        for (int kk = 0; kk < 8; ++kk) {
            bf16x8 a = *(const bf16x8*)(arow + kk * 16);
            acc[m] = __builtin_amdgcn_mfma_f32_32x32x16_bf16(a, wb[kk], acc[m], 0, 0, 0);
        }
    }

    // ---- epilogue: relu(acc + bB) -> bf16 global (masked rows) ----
#pragma unroll
    for (int m = 0; m < 2; ++m) {
#pragma unroll
        for (int r = 0; r < 16; ++r) {
            int rl = (r & 3) + 8 * (r >> 2) + 4 * hk;
            int row = rowBase + m * 32 + rl;
            if (row < nrows)
                C[(size_t)row * 128 + colBase + l32] =
                    bf16of(fmaxf(acc[m][r] + biasB, 0.f));
        }
    }
}

// ---------------------------------------------------------------------------
// Fused pooling + head: one block per graph (1024 threads = 16 waves).
// ---------------------------------------------------------------------------

__global__ __launch_bounds__(1024) void k_poolfinal(const uint* __restrict__ hb,
                                                    const int* __restrict__ sdeg,
                                                    const int* __restrict__ s2nF,
                                                    const int* __restrict__ gcnt,
                                                    const int* __restrict__ g2sF,
                                                    const float* __restrict__ W1,
                                                    const float* __restrict__ b1,
                                                    const float* __restrict__ W2,
                                                    const float* __restrict__ b2,
                                                    float* __restrict__ out) {
    __shared__ float gacc[16][130];   // per-wave accumulators (+pad)
    __shared__ float row[128];
    __shared__ float t1[128];
    __shared__ float red[128];
    const int g = blockIdx.x;
    const int tid = threadIdx.x;
    const int wave = tid >> 6, lane = tid & 63;

    int ns = gcnt[g]; if (ns > 128) ns = 128;
    float ax = 0.f, ay = 0.f;
    for (int si = wave; si < ns; si += 16) {
        int sg = g2sF[(g << 7) + si];
        int ec = sdeg[sg]; if (ec > 32) ec = 32;
        int idx = s2nF[(sg << 5) + ((lane < ec) ? lane : 0)];
        int j = 0;
        for (; j + 3 < ec; j += 4) {
            int n0 = __shfl(idx, j),     n1 = __shfl(idx, j + 1);
            int n2 = __shfl(idx, j + 2), n3 = __shfl(idx, j + 3);
            uint v0 = hb[(size_t)n0 * 64 + lane];
            uint v1 = hb[(size_t)n1 * 64 + lane];
            uint v2 = hb[(size_t)n2 * 64 + lane];
            uint v3 = hb[(size_t)n3 * 64 + lane];
            ax += bflo(v0) + bflo(v1) + bflo(v2) + bflo(v3);
            ay += bfhi(v0) + bfhi(v1) + bfhi(v2) + bfhi(v3);
        }
        for (; j < ec; ++j) {
            int nj = __shfl(idx, j);
            uint v = hb[(size_t)nj * 64 + lane];
            ax += bflo(v); ay += bfhi(v);
        }
    }
    gacc[wave][2 * lane]     = ax;
    gacc[wave][2 * lane + 1] = ay;
    __syncthreads();

    if (tid < 128) {
        float s = 0.f;
#pragma unroll
        for (int w = 0; w < 16; ++w) s += gacc[w][tid];
        row[tid] = s;
    }
    __syncthreads();

    float s2 = 0.f;
    if (tid < 128) {
        float s1 = b1[tid];
        for (int k = 0; k < 128; ++k) s1 = fmaf(row[k], W1[k * 128 + tid], s1);
        t1[tid] = fmaxf(s1, 0.f);
    }
    __syncthreads();
    if (tid < 128) {
        s2 = b2[tid];
        for (int k = 0; k < 128; ++k) s2 = fmaf(t1[k], W2[k * 128 + tid], s2);
        red[tid] = s2;
    }
    __syncthreads();
    for (int off = 64; off > 0; off >>= 1) {
        if (tid < off) red[tid] = fmaxf(red[tid], red[tid + off]);
        __syncthreads();
    }
    float m = red[0];
    __syncthreads();
    if (tid < 128) red[tid] = expf(s2 - m);
    __syncthreads();
    for (int off = 64; off > 0; off >>= 1) {
        if (tid < off) red[tid] += red[tid + off];
        __syncthreads();
    }
    if (tid < 128) out[g * 128 + tid] = s2 - (m + logf(red[0]));
}

// ---------------------------------------------------------------------------

extern "C" void kernel_launch(void* const* d_in, const int* in_sizes, int n_in,
                              void* d_out, int out_size, void* d_ws, size_t ws_size,
                              hipStream_t stream) {
    (void)in_sizes; (void)n_in; (void)out_size; (void)ws_size;
    const float* x    = (const float*)d_in[0];
    const int*   ei   = (const int*)d_in[1];
    const int*   n2s  = (const int*)d_in[2];
    const int*   s2g  = (const int*)d_in[3];
    const float* W1a  = (const float*)d_in[4];
    const float* b1a  = (const float*)d_in[5];
    const float* W1b  = (const float*)d_in[6];
    const float* b1b  = (const float*)d_in[7];
    const float* cWa  = (const float*)d_in[8];
    const float* cba  = (const float*)d_in[9];
    const float* cWb  = (const float*)d_in[10];
    const float* cbb  = (const float*)d_in[11];
    const float* l1W  = (const float*)d_in[12];
    const float* l1b  = (const float*)d_in[13];
    const float* l2W  = (const float*)d_in[14];
    const float* l2b  = (const float*)d_in[15];
    float* out = (float*)d_out;

    // workspace layout (~40 MB)
    uint*  hb      = (uint*)d_ws;                          // N*64 (bf16 h)
    uint*  habuf   = hb + (size_t)N_NODES * 64;            // N*64 (aggr buf)
    int*   csrcF   = (int*)(habuf + (size_t)N_NODES * 64); // N*64 fixed slots
    int*   s2nF    = csrcF + (size_t)N_NODES * 64;         // S*32 fixed slots
    int*   g2sF    = s2nF + SSUB * 32;                     // G*128 fixed slots
    int*   deg     = g2sF + GGRAPH * 128;                  // N   ← memset region
    int*   sdeg    = deg + N_NODES;                        // S
    int*   gcnt    = sdeg + SSUB;                          // G
    int*   chunkCtr= gcnt + GGRAPH;                        // 8 (work-steal ctrs)
    ushort* wt     = (ushort*)(chunkCtr + 8);              // 7*16384 bf16

    const int* srcA = ei;
    const int* dstA = ei + N_EDGES;
    const int nTileBlocks = (N_NODES + 63) / 64;   // 782

    // --- one memset zeroes deg + sdeg + gcnt + chunkCtr (contiguous) ---
    hipMemsetAsync(deg, 0, (size_t)(N_NODES + SSUB + GGRAPH + 8) * 4, stream);

    // --- one prep kernel: edge fill (XCD work-steal) + pool fills + wconv ---
    k_prep<<<PB + NB + SB + WB, 256, 0, stream>>>(srcA, dstA, deg, csrcF, chunkCtr,
                                                  n2s, sdeg, s2nF,
                                                  s2g, gcnt, g2sF,
                                                  W1b, cWa, cWb, wt);

    // --- conv 1 (fully fused, parallel gather) -> hb ---
    k_layer1<<<nTileBlocks, 256, 0, stream>>>((const float2*)x, deg, csrcF,
                                              W1a, b1a, wt, b1b, (ushort*)hb);

    // --- convs 2..4: aggr(hb)->habuf, fused MLP(habuf)->hb ---
    for (int i = 0; i < 3; ++i) {
        k_aggr128_bf16<<<N_NODES / 4, 256, 0, stream>>>(hb, deg, csrcF, habuf);
        k_mlp<<<nTileBlocks, 256, 0, stream>>>((const ushort*)habuf,
                                               wt + (size_t)(1 + i) * 16384,
                                               cba + i * HDIM,
                                               wt + (size_t)(4 + i) * 16384,
                                               cbb + i * HDIM,
                                               (ushort*)hb, N_NODES);
    }

    // --- pooling (both levels) + head, one dispatch ---
    k_poolfinal<<<GGRAPH, 1024, 0, stream>>>(hb, sdeg, s2nF, gcnt, g2sF,
                                             l1W, l1b, l2W, l2b, out);
}

// Round 14
// 329.367 us; speedup vs baseline: 1.1251x; 1.1251x over previous
//
#include <hip/hip_runtime.h>
#include <cstddef>

#define N_NODES  50000
#define N_EDGES  800000
#define HDIM     128
#define SSUB     5000
#define GGRAPH   64
#define FILL_Q   416            // blocks per part in edge fill
#define PB       (8 * FILL_Q)   // 3328 edge-fill blocks
#define LDSW     136            // LDS row stride in ushorts (128 + 8 pad)

#define NB 196                  // node blocks ((50000+255)/256)
#define SB 20                   // subgraph blocks ((5000+255)/256)
#define WB 448                  // wconv blocks (7*16384/256)

typedef unsigned int uint;
typedef unsigned short ushort;
typedef __attribute__((ext_vector_type(8))) short bf16x8;
typedef __attribute__((ext_vector_type(16))) float f32x16;

// bf16 helpers (packed pair in a uint: low ushort = even feature, high = odd)
__device__ __forceinline__ float bflo(uint v) { return __uint_as_float(v << 16); }
__device__ __forceinline__ float bfhi(uint v) { return __uint_as_float(v & 0xffff0000u); }
__device__ __forceinline__ uint packbf(float lo, float hi) {
    uint a = __float_as_uint(lo), b = __float_as_uint(hi);
    a = (a + 0x7fff + ((a >> 16) & 1)) >> 16;          // RNE
    b = (b + 0x7fff + ((b >> 16) & 1)) & 0xffff0000u;  // RNE, keep high half
    return a | b;
}
__device__ __forceinline__ ushort bf16of(float f) {
    uint a = __float_as_uint(f);
    a = (a + 0x7fff + ((a >> 16) & 1)) >> 16;
    return (ushort)a;
}

// ---------------------------------------------------------------------------
// One-shot prep (R12-proven form):
//  part A (PB blocks): XCD-partitioned fixed-slot edge fill. part=blockIdx&7
//    owns dst range [part*6250, +6250). Residual ~8x write amplification is
//    temporal (a node's first csrc line gets ~16 writes spread over the full
//    partition scan) — measured invariant to placement tricks (R13).
//  part B (NB blocks): fixed-slot subgraph fill (cap 32; actual max ~25).
//  part D (SB blocks): fixed-slot subgraph->graph fill (cap 128; max ~110).
//  part C (WB blocks): weight convert -> bf16 transposed wt[m][n][k]=W[k][n].
// ---------------------------------------------------------------------------

__global__ __launch_bounds__(256) void k_prep(const int* __restrict__ src,
                                              const int* __restrict__ dst,
                                              int* __restrict__ deg,
                                              int* __restrict__ csrcF,
                                              const int* __restrict__ n2s,
                                              int* __restrict__ sdeg,
                                              int* __restrict__ s2nF,
                                              const int* __restrict__ s2g,
                                              int* __restrict__ gcnt,
                                              int* __restrict__ g2sF,
                                              const float* __restrict__ W1b,
                                              const float* __restrict__ cWa,
                                              const float* __restrict__ cWb,
                                              ushort* __restrict__ wt) {
    int b = blockIdx.x, t = threadIdx.x;
    if (b < PB) {
        int part = b & 7;
        int q = b >> 3;
        int lo = part * 6250, hi = lo + 6250;
        for (int e = q * 256 + t; e < N_EDGES; e += FILL_Q * 256) {
            int d = dst[e];
            if (d >= lo && d < hi) {
                int pos = atomicAdd(&deg[d], 1);
                if (pos < 64) csrcF[(d << 6) + pos] = src[e];
            }
        }
    } else if (b < PB + NB) {
        int i = (b - PB) * 256 + t;
        if (i < N_NODES) {
            int sg = n2s[i];
            int pos = atomicAdd(&sdeg[sg], 1);
            if (pos < 32) s2nF[(sg << 5) + pos] = i;
        }
    } else if (b < PB + NB + SB) {
        int i = (b - PB - NB) * 256 + t;
        if (i < SSUB) {
            int g = s2g[i];
            int pos = atomicAdd(&gcnt[g], 1);
            if (pos < 128) g2sF[(g << 7) + pos] = i;
        }
    } else {
        int gid = (b - PB - NB - SB) * 256 + t;    // 7*16384 total
        int m = gid >> 14, r = gid & 16383;
        int n = r >> 7, k = r & 127;
        const float* Wsrc = (m == 0) ? W1b
                          : (m <= 3) ? cWa + (size_t)(m - 1) * 16384
                                     : cWb + (size_t)(m - 4) * 16384;
        wt[gid] = bf16of(Wsrc[k * 128 + n]);
    }
}

// ---------------------------------------------------------------------------
// Conv 1, fully fused, parallel gather:
//  1a) 4 threads per node gather x (L2-hot) + shfl_xor reduce -> LDS sums
//  1b) wave-per-16-nodes applies W1a+b1a+relu -> 64x128 bf16 LDS tile
//   2) column-sliced 32x32x16 MFMA gemm (W1b^T slice reg-resident) -> hb
// ---------------------------------------------------------------------------

__global__ __launch_bounds__(256) void k_layer1(const float2* __restrict__ x,
                                                const int* __restrict__ deg,
                                                const int* __restrict__ csrcF,
                                                const float* __restrict__ W1a,
                                                const float* __restrict__ b1a,
                                                const ushort* __restrict__ WtA,
                                                const float* __restrict__ bA,
                                                ushort* __restrict__ hbout) {
    __shared__ ushort lds[64 * LDSW];   // 17.4 KB
    __shared__ float2 sums[64];
    const int tid = threadIdx.x, wave = tid >> 6, lane = tid & 63;
    const int nodeBase = blockIdx.x * 64;

    // ---- phase 1a: 4 threads per node gather + reduce ----
    {
        int nl = tid >> 2, sub = tid & 3;
        int gn = nodeBase + nl;
        float tx = 0.f, ty = 0.f;
        if (gn < N_NODES) {
            int e = deg[gn]; if (e > 64) e = 64;
            for (int k = sub; k < e; k += 4) {
                float2 v = x[csrcF[(gn << 6) + k]];
                tx += v.x; ty += v.y;
            }
        }
        tx += __shfl_xor(tx, 1); ty += __shfl_xor(ty, 1);
        tx += __shfl_xor(tx, 2); ty += __shfl_xor(ty, 2);
        if (sub == 0) {
            if (gn < N_NODES) {
                float2 sv = x[gn];
                sums[nl] = make_float2(tx + sv.x, ty + sv.y);
            } else {
                sums[nl] = make_float2(0.f, 0.f);
            }
        }
    }
    __syncthreads();

    // ---- phase 1b: lin1a + relu -> bf16 LDS tile ----
    {
        float2 wlo = ((const float2*)W1a)[lane];        // W1a[0][2l..2l+1]
        float2 whi = ((const float2*)W1a)[64 + lane];   // W1a[1][2l..2l+1]
        float2 bv  = ((const float2*)b1a)[lane];
        for (int n = wave * 16; n < wave * 16 + 16; ++n) {
            float2 ts = sums[n];
            float v0 = fmaf(ts.x, wlo.x, fmaf(ts.y, whi.x, bv.x));
            float v1 = fmaf(ts.x, wlo.y, fmaf(ts.y, whi.y, bv.y));
            *(uint*)(&lds[n * LDSW + 2 * lane]) = packbf(fmaxf(v0, 0.f), fmaxf(v1, 0.f));
        }
    }

    // ---- register-resident WtA slice ----
    const int l32 = lane & 31, hk = lane >> 5;
    const int colBase = wave * 32;
    bf16x8 wa[8];
#pragma unroll
    for (int kk = 0; kk < 8; ++kk)
        wa[kk] = *(const bf16x8*)(WtA + (size_t)(colBase + l32) * 128 + kk * 16 + hk * 8);
    const float biasA = bA[colBase + l32];
    __syncthreads();

    // ---- phase 2: column-sliced gemm, 2 m-tiles of 32 rows ----
    f32x16 acc[2];
#pragma unroll
    for (int m = 0; m < 2; ++m)
#pragma unroll
        for (int r = 0; r < 16; ++r) acc[m][r] = 0.f;
#pragma unroll
    for (int m = 0; m < 2; ++m) {
        const ushort* arow = lds + (m * 32 + l32) * LDSW + hk * 8;
#pragma unroll
        for (int kk = 0; kk < 8; ++kk) {
            bf16x8 a = *(const bf16x8*)(arow + kk * 16);
            acc[m] = __builtin_amdgcn_mfma_f32_32x32x16_bf16(a, wa[kk], acc[m], 0, 0, 0);
        }
    }

    // ---- epilogue: relu(acc + bA) -> bf16 global (masked rows) ----
#pragma unroll
    for (int m = 0; m < 2; ++m) {
#pragma unroll
        for (int r = 0; r < 16; ++r) {
            int rl = (r & 3) + 8 * (r >> 2) + 4 * hk;
            int row = nodeBase + m * 32 + rl;
            if (row < N_NODES)
                hbout[(size_t)row * 128 + colBase + l32] =
                    bf16of(fmaxf(acc[m][r] + biasA, 0.f));
        }
    }
}

// ---------------------------------------------------------------------------
// GIN aggregation, H=128, bf16 in/out: one wave per node, lane holds one uint
// (2 bf16 features), full 256 B row per gather, shfl broadcast of the
// (aligned) fixed-slot csrc list, up to 16 outstanding gathers.
// ---------------------------------------------------------------------------

__global__ __launch_bounds__(256) void k_aggr128_bf16(const uint* __restrict__ hb,
                                                      const int* __restrict__ deg,
                                                      const int* __restrict__ csrcF,
                                                      uint* __restrict__ out) {
    int node = blockIdx.x * 4 + (threadIdx.x >> 6);   // grid = N/4 exact
    int lane = threadIdx.x & 63;
    int cnt = deg[node]; if (cnt > 64) cnt = 64;
    uint sv = hb[(size_t)node * 64 + lane];
    float ax0 = bflo(sv), ay0 = bfhi(sv);
    float ax1 = 0.f, ay1 = 0.f, ax2 = 0.f, ay2 = 0.f, ax3 = 0.f, ay3 = 0.f;
    int idx = csrcF[(node << 6) + ((lane < cnt) ? lane : 0)];   // aligned 256 B load
    int j = 0;
    for (; j + 15 < cnt; j += 16) {                     // 16 outstanding gathers
        int s0 = __shfl(idx, j),      s1 = __shfl(idx, j + 1);
        int s2 = __shfl(idx, j + 2),  s3 = __shfl(idx, j + 3);
        int s4 = __shfl(idx, j + 4),  s5 = __shfl(idx, j + 5);
        int s6 = __shfl(idx, j + 6),  s7 = __shfl(idx, j + 7);
        int s8 = __shfl(idx, j + 8),  s9 = __shfl(idx, j + 9);
        int sa = __shfl(idx, j + 10), sb = __shfl(idx, j + 11);
        int sc = __shfl(idx, j + 12), sd = __shfl(idx, j + 13);
        int se = __shfl(idx, j + 14), sf = __shfl(idx, j + 15);
        uint v0 = hb[(size_t)s0 * 64 + lane];
        uint v1 = hb[(size_t)s1 * 64 + lane];
        uint v2 = hb[(size_t)s2 * 64 + lane];
        uint v3 = hb[(size_t)s3 * 64 + lane];
        uint v4 = hb[(size_t)s4 * 64 + lane];
        uint v5 = hb[(size_t)s5 * 64 + lane];
        uint v6 = hb[(size_t)s6 * 64 + lane];
        uint v7 = hb[(size_t)s7 * 64 + lane];
        uint v8 = hb[(size_t)s8 * 64 + lane];
        uint v9 = hb[(size_t)s9 * 64 + lane];
        uint va = hb[(size_t)sa * 64 + lane];
        uint vb = hb[(size_t)sb * 64 + lane];
        uint vc = hb[(size_t)sc * 64 + lane];
        uint vd = hb[(size_t)sd * 64 + lane];
        uint ve = hb[(size_t)se * 64 + lane];
        uint vf = hb[(size_t)sf * 64 + lane];
        ax0 += bflo(v0); ay0 += bfhi(v0);
        ax1 += bflo(v1); ay1 += bfhi(v1);
        ax2 += bflo(v2); ay2 += bfhi(v2);
        ax3 += bflo(v3); ay3 += bfhi(v3);
        ax0 += bflo(v4); ay0 += bfhi(v4);
        ax1 += bflo(v5); ay1 += bfhi(v5);
        ax2 += bflo(v6); ay2 += bfhi(v6);
        ax3 += bflo(v7); ay3 += bfhi(v7);
        ax0 += bflo(v8); ay0 += bfhi(v8);
        ax1 += bflo(v9); ay1 += bfhi(v9);
        ax2 += bflo(va); ay2 += bfhi(va);
        ax3 += bflo(vb); ay3 += bfhi(vb);
        ax0 += bflo(vc); ay0 += bfhi(vc);
        ax1 += bflo(vd); ay1 += bfhi(vd);
        ax2 += bflo(ve); ay2 += bfhi(ve);
        ax3 += bflo(vf); ay3 += bfhi(vf);
    }
    for (; j + 3 < cnt; j += 4) {
        int s0 = __shfl(idx, j),     s1 = __shfl(idx, j + 1);
        int s2 = __shfl(idx, j + 2), s3 = __shfl(idx, j + 3);
        uint v0 = hb[(size_t)s0 * 64 + lane];
        uint v1 = hb[(size_t)s1 * 64 + lane];
        uint v2 = hb[(size_t)s2 * 64 + lane];
        uint v3 = hb[(size_t)s3 * 64 + lane];
        ax0 += bflo(v0); ay0 += bfhi(v0);
        ax1 += bflo(v1); ay1 += bfhi(v1);
        ax2 += bflo(v2); ay2 += bfhi(v2);
        ax3 += bflo(v3); ay3 += bfhi(v3);
    }
    for (; j < cnt; ++j) {
        int sj = __shfl(idx, j);
        uint v = hb[(size_t)sj * 64 + lane];
        ax0 += bflo(v); ay0 += bfhi(v);
    }
    out[(size_t)node * 64 + lane] =
        packbf((ax0 + ax1) + (ax2 + ax3), (ay0 + ay1) + (ay2 + ay3));
}

// ---------------------------------------------------------------------------
// Fused GIN MLP — 64-row blocks, column-sliced 32x32x16 MFMA, B register-
// resident. gemmA reads A DIRECTLY from row-major global (A-frag is a 16 B
// contiguous load; each row L2-hit by 4 waves) — no staging, no stage
// barrier. Intermediate relu tile in LDS (one barrier), then gemmB.
// ---------------------------------------------------------------------------

__global__ __launch_bounds__(256) void k_mlp(const ushort* __restrict__ A,
                                             const ushort* __restrict__ WtA,
                                             const float* __restrict__ bA,
                                             const ushort* __restrict__ WtB,
                                             const float* __restrict__ bB,
                                             ushort* __restrict__ C, int nrows) {
    __shared__ ushort ldsB[64 * LDSW];   // intermediate tile (17.4 KB)
    const int tid = threadIdx.x;
    const int wave = tid >> 6, lane = tid & 63;
    const int l32 = lane & 31, hk = lane >> 5;
    const int colBase = wave * 32;
    const int rowBase = blockIdx.x * 64;

    // ---- register-resident Wt slices (loaded once, L2-hot) ----
    bf16x8 wa[8], wb[8];
#pragma unroll
    for (int kk = 0; kk < 8; ++kk) {
        wa[kk] = *(const bf16x8*)(WtA + (size_t)(colBase + l32) * 128 + kk * 16 + hk * 8);
        wb[kk] = *(const bf16x8*)(WtB + (size_t)(colBase + l32) * 128 + kk * 16 + hk * 8);
    }
    const float biasA = bA[colBase + l32];
    const float biasB = bB[colBase + l32];

    // ---- gemm A (A-frags straight from global, 4x L2 reuse per row) ----
    f32x16 acc[2];
#pragma unroll
    for (int m = 0; m < 2; ++m)
#pragma unroll
        for (int r = 0; r < 16; ++r) acc[m][r] = 0.f;
#pragma unroll
    for (int m = 0; m < 2; ++m) {
        const int row = rowBase + m * 32 + l32;
        const bool valid = row < nrows;
        const ushort* arow = A + (size_t)row * 128 + hk * 8;
#pragma unroll
        for (int kk = 0; kk < 8; ++kk) {
            bf16x8 a = valid ? *(const bf16x8*)(arow + kk * 16)
                             : (bf16x8){0,0,0,0,0,0,0,0};
            acc[m] = __builtin_amdgcn_mfma_f32_32x32x16_bf16(a, wa[kk], acc[m], 0, 0, 0);
        }
    }

    // ---- relu(acc + bA) -> ldsB (each wave writes its own column slice) ----
#pragma unroll
    for (int m = 0; m < 2; ++m) {
#pragma unroll
        for (int r = 0; r < 16; ++r) {
            int rl = (r & 3) + 8 * (r >> 2) + 4 * hk;
            ldsB[(m * 32 + rl) * LDSW + colBase + l32] =
                bf16of(fmaxf(acc[m][r] + biasA, 0.f));
        }
    }
    __syncthreads();

    // ---- gemm B (reads full rows of ldsB) ----
#pragma unroll
    for (int m = 0; m < 2; ++m)
#pragma unroll
        for (int r = 0; r < 16; ++r) acc[m][r] = 0.f;
#pragma unroll
    for (int m = 0; m < 2; ++m) {
        const ushort* arow = ldsB + (m * 32 + l32) * LDSW + hk * 8;
#pragma unroll
        for (int kk = 0; kk < 8; ++kk) {
            bf16x8 a = *(const bf16x8*)(arow + kk * 16);
            acc[m] = __builtin_amdgcn_mfma_f32_32x32x16_bf16(a, wb[kk], acc[m], 0, 0, 0);
        }
    }

    // ---- epilogue: relu(acc + bB) -> bf16 global (masked rows) ----
#pragma unroll
    for (int m = 0; m < 2; ++m) {
#pragma unroll
        for (int r = 0; r < 16; ++r) {
            int rl = (r & 3) + 8 * (r >> 2) + 4 * hk;
            int row = rowBase + m * 32 + rl;
            if (row < nrows)
                C[(size_t)row * 128 + colBase + l32] =
                    bf16of(fmaxf(acc[m][r] + biasB, 0.f));
        }
    }
}

// ---------------------------------------------------------------------------
// Fused pooling + head: one block per graph (1024 threads = 16 waves).
// ---------------------------------------------------------------------------

__global__ __launch_bounds__(1024) void k_poolfinal(const uint* __restrict__ hb,
                                                    const int* __restrict__ sdeg,
                                                    const int* __restrict__ s2nF,
                                                    const int* __restrict__ gcnt,
                                                    const int* __restrict__ g2sF,
                                                    const float* __restrict__ W1,
                                                    const float* __restrict__ b1,
                                                    const float* __restrict__ W2,
                                                    const float* __restrict__ b2,
                                                    float* __restrict__ out) {
    __shared__ float gacc[16][130];   // per-wave accumulators (+pad)
    __shared__ float row[128];
    __shared__ float t1[128];
    __shared__ float red[128];
    const int g = blockIdx.x;
    const int tid = threadIdx.x;
    const int wave = tid >> 6, lane = tid & 63;

    int ns = gcnt[g]; if (ns > 128) ns = 128;
    float ax = 0.f, ay = 0.f;
    for (int si = wave; si < ns; si += 16) {
        int sg = g2sF[(g << 7) + si];
        int ec = sdeg[sg]; if (ec > 32) ec = 32;
        int idx = s2nF[(sg << 5) + ((lane < ec) ? lane : 0)];
        int j = 0;
        for (; j + 3 < ec; j += 4) {
            int n0 = __shfl(idx, j),     n1 = __shfl(idx, j + 1);
            int n2 = __shfl(idx, j + 2), n3 = __shfl(idx, j + 3);
            uint v0 = hb[(size_t)n0 * 64 + lane];
            uint v1 = hb[(size_t)n1 * 64 + lane];
            uint v2 = hb[(size_t)n2 * 64 + lane];
            uint v3 = hb[(size_t)n3 * 64 + lane];
            ax += bflo(v0) + bflo(v1) + bflo(v2) + bflo(v3);
            ay += bfhi(v0) + bfhi(v1) + bfhi(v2) + bfhi(v3);
        }
        for (; j < ec; ++j) {
            int nj = __shfl(idx, j);
            uint v = hb[(size_t)nj * 64 + lane];
            ax += bflo(v); ay += bfhi(v);
        }
    }
    gacc[wave][2 * lane]     = ax;
    gacc[wave][2 * lane + 1] = ay;
    __syncthreads();

    if (tid < 128) {
        float s = 0.f;
#pragma unroll
        for (int w = 0; w < 16; ++w) s += gacc[w][tid];
        row[tid] = s;
    }
    __syncthreads();

    float s2 = 0.f;
    if (tid < 128) {
        float s1 = b1[tid];
        for (int k = 0; k < 128; ++k) s1 = fmaf(row[k], W1[k * 128 + tid], s1);
        t1[tid] = fmaxf(s1, 0.f);
    }
    __syncthreads();
    if (tid < 128) {
        s2 = b2[tid];
        for (int k = 0; k < 128; ++k) s2 = fmaf(t1[k], W2[k * 128 + tid], s2);
        red[tid] = s2;
    }
    __syncthreads();
    for (int off = 64; off > 0; off >>= 1) {
        if (tid < off) red[tid] = fmaxf(red[tid], red[tid + off]);
        __syncthreads();
    }
    float m = red[0];
    __syncthreads();
    if (tid < 128) red[tid] = expf(s2 - m);
    __syncthreads();
    for (int off = 64; off > 0; off >>= 1) {
        if (tid < off) red[tid] += red[tid + off];
        __syncthreads();
    }
    if (tid < 128) out[g * 128 + tid] = s2 - (m + logf(red[0]));
}

// ---------------------------------------------------------------------------

extern "C" void kernel_launch(void* const* d_in, const int* in_sizes, int n_in,
                              void* d_out, int out_size, void* d_ws, size_t ws_size,
                              hipStream_t stream) {
    (void)in_sizes; (void)n_in; (void)out_size; (void)ws_size;
    const float* x    = (const float*)d_in[0];
    const int*   ei   = (const int*)d_in[1];
    const int*   n2s  = (const int*)d_in[2];
    const int*   s2g  = (const int*)d_in[3];
    const float* W1a  = (const float*)d_in[4];
    const float* b1a  = (const float*)d_in[5];
    const float* W1b  = (const float*)d_in[6];
    const float* b1b  = (const float*)d_in[7];
    const float* cWa  = (const float*)d_in[8];
    const float* cba  = (const float*)d_in[9];
    const float* cWb  = (const float*)d_in[10];
    const float* cbb  = (const float*)d_in[11];
    const float* l1W  = (const float*)d_in[12];
    const float* l1b  = (const float*)d_in[13];
    const float* l2W  = (const float*)d_in[14];
    const float* l2b  = (const float*)d_in[15];
    float* out = (float*)d_out;

    // workspace layout (~40 MB)
    uint*  hb    = (uint*)d_ws;                          // N*64 (bf16 h)
    uint*  habuf = hb + (size_t)N_NODES * 64;            // N*64 (aggr buf)
    int*   csrcF = (int*)(habuf + (size_t)N_NODES * 64); // N*64 fixed slots
    int*   s2nF  = csrcF + (size_t)N_NODES * 64;         // S*32 fixed slots
    int*   g2sF  = s2nF + SSUB * 32;                     // G*128 fixed slots
    int*   deg   = g2sF + GGRAPH * 128;                  // N   ← memset region
    int*   sdeg  = deg + N_NODES;                        // S
    int*   gcnt  = sdeg + SSUB;                          // G
    ushort* wt   = (ushort*)(gcnt + GGRAPH);             // 7*16384 bf16

    const int* srcA = ei;
    const int* dstA = ei + N_EDGES;
    const int nTileBlocks = (N_NODES + 63) / 64;   // 782

    // --- one memset zeroes deg + sdeg + gcnt (contiguous) ---
    hipMemsetAsync(deg, 0, (size_t)(N_NODES + SSUB + GGRAPH) * 4, stream);

    // --- one prep kernel: edge fill + subgraph fill + graph fill + wconv ---
    k_prep<<<PB + NB + SB + WB, 256, 0, stream>>>(srcA, dstA, deg, csrcF,
                                                  n2s, sdeg, s2nF,
                                                  s2g, gcnt, g2sF,
                                                  W1b, cWa, cWb, wt);

    // --- conv 1 (fully fused, parallel gather) -> hb ---
    k_layer1<<<nTileBlocks, 256, 0, stream>>>((const float2*)x, deg, csrcF,
                                              W1a, b1a, wt, b1b, (ushort*)hb);

    // --- convs 2..4: aggr(hb)->habuf, fused MLP(habuf)->hb ---
    for (int i = 0; i < 3; ++i) {
        k_aggr128_bf16<<<N_NODES / 4, 256, 0, stream>>>(hb, deg, csrcF, habuf);
        k_mlp<<<nTileBlocks, 256, 0, stream>>>((const ushort*)habuf,
                                               wt + (size_t)(1 + i) * 16384,
                                               cba + i * HDIM,
                                               wt + (size_t)(4 + i) * 16384,
                                               cbb + i * HDIM,
                                               (ushort*)hb, N_NODES);
    }

    // --- pooling (both levels) + head, one dispatch ---
    k_poolfinal<<<GGRAPH, 1024, 0, stream>>>(hb, sdeg, s2nF, gcnt, g2sF,
                                             l1W, l1b, l2W, l2b, out);
}

// Round 15
// 317.569 us; speedup vs baseline: 1.1669x; 1.0372x over previous
//
#include <hip/hip_runtime.h>
#include <cstddef>

#define N_NODES  50000
#define N_EDGES  800000
#define HDIM     128
#define SSUB     5000
#define GGRAPH   64
#define FILL_Q   416            // blocks per part in edge fill
#define PB       (8 * FILL_Q)   // 3328 edge-fill blocks
#define LDSW     136            // LDS row stride in ushorts (128 + 8 pad)

#define NB 196                  // node blocks ((50000+255)/256)
#define SB 20                   // subgraph blocks ((5000+255)/256)
#define WB 448                  // wconv blocks (7*16384/256)

typedef unsigned int uint;
typedef unsigned short ushort;
typedef __attribute__((ext_vector_type(8))) short bf16x8;
typedef __attribute__((ext_vector_type(16))) float f32x16;

// bf16 helpers (packed pair in a uint: low ushort = even feature, high = odd)
__device__ __forceinline__ float bflo(uint v) { return __uint_as_float(v << 16); }
__device__ __forceinline__ float bfhi(uint v) { return __uint_as_float(v & 0xffff0000u); }
__device__ __forceinline__ uint packbf(float lo, float hi) {
    uint a = __float_as_uint(lo), b = __float_as_uint(hi);
    a = (a + 0x7fff + ((a >> 16) & 1)) >> 16;          // RNE
    b = (b + 0x7fff + ((b >> 16) & 1)) & 0xffff0000u;  // RNE, keep high half
    return a | b;
}
__device__ __forceinline__ ushort bf16of(float f) {
    uint a = __float_as_uint(f);
    a = (a + 0x7fff + ((a >> 16) & 1)) >> 16;
    return (ushort)a;
}

// ---------------------------------------------------------------------------
// One-shot prep:
//  part A (PB blocks): XCD-partitioned fixed-slot edge fill. part=blockIdx&7
//    owns dst range [part*6250, +6250). src/dst loaded NON-TEMPORALLY so the
//    6.4 MB/partition streaming reads don't evict the 1.6 MB scatter window
//    from L2 (the write amplification is temporal eviction — R13/R14).
//  part B (NB blocks): fixed-slot subgraph fill (cap 32; actual max ~25).
//  part D (SB blocks): fixed-slot subgraph->graph fill (cap 128; max ~110).
//  part C (WB blocks): weight convert -> bf16 transposed wt[m][n][k]=W[k][n].
// ---------------------------------------------------------------------------

__global__ __launch_bounds__(256) void k_prep(const int* __restrict__ src,
                                              const int* __restrict__ dst,
                                              int* __restrict__ deg,
                                              int* __restrict__ csrcF,
                                              const int* __restrict__ n2s,
                                              int* __restrict__ sdeg,
                                              int* __restrict__ s2nF,
                                              const int* __restrict__ s2g,
                                              int* __restrict__ gcnt,
                                              int* __restrict__ g2sF,
                                              const float* __restrict__ W1b,
                                              const float* __restrict__ cWa,
                                              const float* __restrict__ cWb,
                                              ushort* __restrict__ wt) {
    int b = blockIdx.x, t = threadIdx.x;
    if (b < PB) {
        int part = b & 7;
        int q = b >> 3;
        int lo = part * 6250, hi = lo + 6250;
        for (int e = q * 256 + t; e < N_EDGES; e += FILL_Q * 256) {
            int d = __builtin_nontemporal_load(&dst[e]);
            if (d >= lo && d < hi) {
                int s = __builtin_nontemporal_load(&src[e]);
                int pos = atomicAdd(&deg[d], 1);
                if (pos < 64) csrcF[(d << 6) + pos] = s;
            }
        }
    } else if (b < PB + NB) {
        int i = (b - PB) * 256 + t;
        if (i < N_NODES) {
            int sg = n2s[i];
            int pos = atomicAdd(&sdeg[sg], 1);
            if (pos < 32) s2nF[(sg << 5) + pos] = i;
        }
    } else if (b < PB + NB + SB) {
        int i = (b - PB - NB) * 256 + t;
        if (i < SSUB) {
            int g = s2g[i];
            int pos = atomicAdd(&gcnt[g], 1);
            if (pos < 128) g2sF[(g << 7) + pos] = i;
        }
    } else {
        int gid = (b - PB - NB - SB) * 256 + t;    // 7*16384 total
        int m = gid >> 14, r = gid & 16383;
        int n = r >> 7, k = r & 127;
        const float* Wsrc = (m == 0) ? W1b
                          : (m <= 3) ? cWa + (size_t)(m - 1) * 16384
                                     : cWb + (size_t)(m - 4) * 16384;
        wt[gid] = bf16of(Wsrc[k * 128 + n]);
    }
}

// ---------------------------------------------------------------------------
// Conv 1, fully fused, parallel gather:
//  1a) 4 threads per node gather x (L2-hot) + shfl_xor reduce -> LDS sums
//  1b) wave-per-16-nodes applies W1a+b1a+relu -> 64x128 bf16 LDS tile
//   2) column-sliced 32x32x16 MFMA gemm (W1b^T slice reg-resident) -> hb
// ---------------------------------------------------------------------------

__global__ __launch_bounds__(256) void k_layer1(const float2* __restrict__ x,
                                                const int* __restrict__ deg,
                                                const int* __restrict__ csrcF,
                                                const float* __restrict__ W1a,
                                                const float* __restrict__ b1a,
                                                const ushort* __restrict__ WtA,
                                                const float* __restrict__ bA,
                                                ushort* __restrict__ hbout) {
    __shared__ ushort lds[64 * LDSW];   // 17.4 KB
    __shared__ float2 sums[64];
    const int tid = threadIdx.x, wave = tid >> 6, lane = tid & 63;
    const int nodeBase = blockIdx.x * 64;

    // ---- phase 1a: 4 threads per node gather + reduce ----
    {
        int nl = tid >> 2, sub = tid & 3;
        int gn = nodeBase + nl;
        float tx = 0.f, ty = 0.f;
        if (gn < N_NODES) {
            int e = deg[gn]; if (e > 64) e = 64;
            for (int k = sub; k < e; k += 4) {
                float2 v = x[csrcF[(gn << 6) + k]];
                tx += v.x; ty += v.y;
            }
        }
        tx += __shfl_xor(tx, 1); ty += __shfl_xor(ty, 1);
        tx += __shfl_xor(tx, 2); ty += __shfl_xor(ty, 2);
        if (sub == 0) {
            if (gn < N_NODES) {
                float2 sv = x[gn];
                sums[nl] = make_float2(tx + sv.x, ty + sv.y);
            } else {
                sums[nl] = make_float2(0.f, 0.f);
            }
        }
    }
    __syncthreads();

    // ---- phase 1b: lin1a + relu -> bf16 LDS tile ----
    {
        float2 wlo = ((const float2*)W1a)[lane];        // W1a[0][2l..2l+1]
        float2 whi = ((const float2*)W1a)[64 + lane];   // W1a[1][2l..2l+1]
        float2 bv  = ((const float2*)b1a)[lane];
        for (int n = wave * 16; n < wave * 16 + 16; ++n) {
            float2 ts = sums[n];
            float v0 = fmaf(ts.x, wlo.x, fmaf(ts.y, whi.x, bv.x));
            float v1 = fmaf(ts.x, wlo.y, fmaf(ts.y, whi.y, bv.y));
            *(uint*)(&lds[n * LDSW + 2 * lane]) = packbf(fmaxf(v0, 0.f), fmaxf(v1, 0.f));
        }
    }

    // ---- register-resident WtA slice ----
    const int l32 = lane & 31, hk = lane >> 5;
    const int colBase = wave * 32;
    bf16x8 wa[8];
#pragma unroll
    for (int kk = 0; kk < 8; ++kk)
        wa[kk] = *(const bf16x8*)(WtA + (size_t)(colBase + l32) * 128 + kk * 16 + hk * 8);
    const float biasA = bA[colBase + l32];
    __syncthreads();

    // ---- phase 2: column-sliced gemm, 2 m-tiles of 32 rows ----
    f32x16 acc[2];
#pragma unroll
    for (int m = 0; m < 2; ++m)
#pragma unroll
        for (int r = 0; r < 16; ++r) acc[m][r] = 0.f;
#pragma unroll
    for (int m = 0; m < 2; ++m) {
        const ushort* arow = lds + (m * 32 + l32) * LDSW + hk * 8;
#pragma unroll
        for (int kk = 0; kk < 8; ++kk) {
            bf16x8 a = *(const bf16x8*)(arow + kk * 16);
            acc[m] = __builtin_amdgcn_mfma_f32_32x32x16_bf16(a, wa[kk], acc[m], 0, 0, 0);
        }
    }

    // ---- epilogue: relu(acc + bA) -> bf16 global (masked rows) ----
#pragma unroll
    for (int m = 0; m < 2; ++m) {
#pragma unroll
        for (int r = 0; r < 16; ++r) {
            int rl = (r & 3) + 8 * (r >> 2) + 4 * hk;
            int row = nodeBase + m * 32 + rl;
            if (row < N_NODES)
                hbout[(size_t)row * 128 + colBase + l32] =
                    bf16of(fmaxf(acc[m][r] + biasA, 0.f));
        }
    }
}

// ---------------------------------------------------------------------------
// GIN aggregation, H=128, bf16 in/out: one wave per node, lane holds one uint
// (2 bf16 features), full 256 B row per gather, shfl broadcast of the
// (aligned) fixed-slot csrc list, up to 16 outstanding gathers.
// ---------------------------------------------------------------------------

__global__ __launch_bounds__(256) void k_aggr128_bf16(const uint* __restrict__ hb,
                                                      const int* __restrict__ deg,
                                                      const int* __restrict__ csrcF,
                                                      uint* __restrict__ out) {
    int node = blockIdx.x * 4 + (threadIdx.x >> 6);   // grid = N/4 exact
    int lane = threadIdx.x & 63;
    int cnt = deg[node]; if (cnt > 64) cnt = 64;
    uint sv = hb[(size_t)node * 64 + lane];
    float ax0 = bflo(sv), ay0 = bfhi(sv);
    float ax1 = 0.f, ay1 = 0.f, ax2 = 0.f, ay2 = 0.f, ax3 = 0.f, ay3 = 0.f;
    int idx = csrcF[(node << 6) + ((lane < cnt) ? lane : 0)];   // aligned 256 B load
    int j = 0;
    for (; j + 15 < cnt; j += 16) {                     // 16 outstanding gathers
        int s0 = __shfl(idx, j),      s1 = __shfl(idx, j + 1);
        int s2 = __shfl(idx, j + 2),  s3 = __shfl(idx, j + 3);
        int s4 = __shfl(idx, j + 4),  s5 = __shfl(idx, j + 5);
        int s6 = __shfl(idx, j + 6),  s7 = __shfl(idx, j + 7);
        int s8 = __shfl(idx, j + 8),  s9 = __shfl(idx, j + 9);
        int sa = __shfl(idx, j + 10), sb = __shfl(idx, j + 11);
        int sc = __shfl(idx, j + 12), sd = __shfl(idx, j + 13);
        int se = __shfl(idx, j + 14), sf = __shfl(idx, j + 15);
        uint v0 = hb[(size_t)s0 * 64 + lane];
        uint v1 = hb[(size_t)s1 * 64 + lane];
        uint v2 = hb[(size_t)s2 * 64 + lane];
        uint v3 = hb[(size_t)s3 * 64 + lane];
        uint v4 = hb[(size_t)s4 * 64 + lane];
        uint v5 = hb[(size_t)s5 * 64 + lane];
        uint v6 = hb[(size_t)s6 * 64 + lane];
        uint v7 = hb[(size_t)s7 * 64 + lane];
        uint v8 = hb[(size_t)s8 * 64 + lane];
        uint v9 = hb[(size_t)s9 * 64 + lane];
        uint va = hb[(size_t)sa * 64 + lane];
        uint vb = hb[(size_t)sb * 64 + lane];
        uint vc = hb[(size_t)sc * 64 + lane];
        uint vd = hb[(size_t)sd * 64 + lane];
        uint ve = hb[(size_t)se * 64 + lane];
        uint vf = hb[(size_t)sf * 64 + lane];
        ax0 += bflo(v0); ay0 += bfhi(v0);
        ax1 += bflo(v1); ay1 += bfhi(v1);
        ax2 += bflo(v2); ay2 += bfhi(v2);
        ax3 += bflo(v3); ay3 += bfhi(v3);
        ax0 += bflo(v4); ay0 += bfhi(v4);
        ax1 += bflo(v5); ay1 += bfhi(v5);
        ax2 += bflo(v6); ay2 += bfhi(v6);
        ax3 += bflo(v7); ay3 += bfhi(v7);
        ax0 += bflo(v8); ay0 += bfhi(v8);
        ax1 += bflo(v9); ay1 += bfhi(v9);
        ax2 += bflo(va); ay2 += bfhi(va);
        ax3 += bflo(vb); ay3 += bfhi(vb);
        ax0 += bflo(vc); ay0 += bfhi(vc);
        ax1 += bflo(vd); ay1 += bfhi(vd);
        ax2 += bflo(ve); ay2 += bfhi(ve);
        ax3 += bflo(vf); ay3 += bfhi(vf);
    }
    for (; j + 3 < cnt; j += 4) {
        int s0 = __shfl(idx, j),     s1 = __shfl(idx, j + 1);
        int s2 = __shfl(idx, j + 2), s3 = __shfl(idx, j + 3);
        uint v0 = hb[(size_t)s0 * 64 + lane];
        uint v1 = hb[(size_t)s1 * 64 + lane];
        uint v2 = hb[(size_t)s2 * 64 + lane];
        uint v3 = hb[(size_t)s3 * 64 + lane];
        ax0 += bflo(v0); ay0 += bfhi(v0);
        ax1 += bflo(v1); ay1 += bfhi(v1);
        ax2 += bflo(v2); ay2 += bfhi(v2);
        ax3 += bflo(v3); ay3 += bfhi(v3);
    }
    for (; j < cnt; ++j) {
        int sj = __shfl(idx, j);
        uint v = hb[(size_t)sj * 64 + lane];
        ax0 += bflo(v); ay0 += bfhi(v);
    }
    out[(size_t)node * 64 + lane] =
        packbf((ax0 + ax1) + (ax2 + ax3), (ay0 + ay1) + (ay2 + ay3));
}

// ---------------------------------------------------------------------------
// Fused GIN MLP — R12-proven form: 64-row blocks, column-sliced 32x32x16
// MFMA, B register-resident, coalesced LDS staging of A (scattered-global
// A-frags measured slower — R14). Two LDS regions -> 2 barriers.
// ---------------------------------------------------------------------------

__global__ __launch_bounds__(256) void k_mlp(const ushort* __restrict__ A,
                                             const ushort* __restrict__ WtA,
                                             const float* __restrict__ bA,
                                             const ushort* __restrict__ WtB,
                                             const float* __restrict__ bB,
                                             ushort* __restrict__ C, int nrows) {
    __shared__ ushort ldsA[64 * LDSW];   // input tile (17.4 KB)
    __shared__ ushort ldsB[64 * LDSW];   // intermediate tile (17.4 KB)
    const int tid = threadIdx.x;
    const int wave = tid >> 6, lane = tid & 63;
    const int l32 = lane & 31, hk = lane >> 5;
    const int colBase = wave * 32;
    const int rowBase = blockIdx.x * 64;

    // ---- stage A tile into ldsA (thread t: row t>>2, 64 B quarter) ----
    {
        int r = tid >> 2;
        int qo = (tid & 3) * 32;                    // ushort offset (64 B quarter)
        const uint4* gp = (const uint4*)(A + (size_t)(rowBase + r) * 128 + qo);
        uint4* lp = (uint4*)(ldsA + r * LDSW + qo);
        bool valid = (rowBase + r) < nrows;
#pragma unroll
        for (int q = 0; q < 4; ++q) {
            uint4 v = valid ? gp[q] : (uint4){0u, 0u, 0u, 0u};
            lp[q] = v;
        }
    }

    // ---- register-resident Wt slices (loaded once, L2-hot) ----
    bf16x8 wa[8], wb[8];
#pragma unroll
    for (int kk = 0; kk < 8; ++kk) {
        wa[kk] = *(const bf16x8*)(WtA + (size_t)(colBase + l32) * 128 + kk * 16 + hk * 8);
        wb[kk] = *(const bf16x8*)(WtB + (size_t)(colBase + l32) * 128 + kk * 16 + hk * 8);
    }
    const float biasA = bA[colBase + l32];
    const float biasB = bB[colBase + l32];
    __syncthreads();

    // ---- gemm A (reads ldsA) ----
    f32x16 acc[2];
#pragma unroll
    for (int m = 0; m < 2; ++m)
#pragma unroll
        for (int r = 0; r < 16; ++r) acc[m][r] = 0.f;
#pragma unroll
    for (int m = 0; m < 2; ++m) {
        const ushort* arow = ldsA + (m * 32 + l32) * LDSW + hk * 8;
#pragma unroll
        for (int kk = 0; kk < 8; ++kk) {
            bf16x8 a = *(const bf16x8*)(arow + kk * 16);
            acc[m] = __builtin_amdgcn_mfma_f32_32x32x16_bf16(a, wa[kk], acc[m], 0, 0, 0);
        }
    }

    // ---- relu(acc + bA) -> ldsB ----
#pragma unroll
    for (int m = 0; m < 2; ++m) {
#pragma unroll
        for (int r = 0; r < 16; ++r) {
            int rl = (r & 3) + 8 * (r >> 2) + 4 * hk;
            ldsB[(m * 32 + rl) * LDSW + colBase + l32] =
                bf16of(fmaxf(acc[m][r] + biasA, 0.f));
        }
    }
    __syncthreads();

    // ---- gemm B (reads ldsB) ----
#pragma unroll
    for (int m = 0; m < 2; ++m)
#pragma unroll
        for (int r = 0; r < 16; ++r) acc[m][r] = 0.f;
#pragma unroll
    for (int m = 0; m < 2; ++m) {
        const ushort* arow = ldsB + (m * 32 + l32) * LDSW + hk * 8;
#pragma unroll
        for (int kk = 0; kk < 8; ++kk) {
            bf16x8 a = *(const bf16x8*)(arow + kk * 16);
            acc[m] = __builtin_amdgcn_mfma_f32_32x32x16_bf16(a, wb[kk], acc[m], 0, 0, 0);
        }
    }

    // ---- epilogue: relu(acc + bB) -> bf16 global (masked rows) ----
#pragma unroll
    for (int m = 0; m < 2; ++m) {
#pragma unroll
        for (int r = 0; r < 16; ++r) {
            int rl = (r & 3) + 8 * (r >> 2) + 4 * hk;
            int row = rowBase + m * 32 + rl;
            if (row < nrows)
                C[(size_t)row * 128 + colBase + l32] =
                    bf16of(fmaxf(acc[m][r] + biasB, 0.f));
        }
    }
}

// ---------------------------------------------------------------------------
// Fused pooling + head: one block per graph (1024 threads = 16 waves).
// ---------------------------------------------------------------------------

__global__ __launch_bounds__(1024) void k_poolfinal(const uint* __restrict__ hb,
                                                    const int* __restrict__ sdeg,
                                                    const int* __restrict__ s2nF,
                                                    const int* __restrict__ gcnt,
                                                    const int* __restrict__ g2sF,
                                                    const float* __restrict__ W1,
                                                    const float* __restrict__ b1,
                                                    const float* __restrict__ W2,
                                                    const float* __restrict__ b2,
                                                    float* __restrict__ out) {
    __shared__ float gacc[16][130];   // per-wave accumulators (+pad)
    __shared__ float row[128];
    __shared__ float t1[128];
    __shared__ float red[128];
    const int g = blockIdx.x;
    const int tid = threadIdx.x;
    const int wave = tid >> 6, lane = tid & 63;

    int ns = gcnt[g]; if (ns > 128) ns = 128;
    float ax = 0.f, ay = 0.f;
    for (int si = wave; si < ns; si += 16) {
        int sg = g2sF[(g << 7) + si];
        int ec = sdeg[sg]; if (ec > 32) ec = 32;
        int idx = s2nF[(sg << 5) + ((lane < ec) ? lane : 0)];
        int j = 0;
        for (; j + 3 < ec; j += 4) {
            int n0 = __shfl(idx, j),     n1 = __shfl(idx, j + 1);
            int n2 = __shfl(idx, j + 2), n3 = __shfl(idx, j + 3);
            uint v0 = hb[(size_t)n0 * 64 + lane];
            uint v1 = hb[(size_t)n1 * 64 + lane];
            uint v2 = hb[(size_t)n2 * 64 + lane];
            uint v3 = hb[(size_t)n3 * 64 + lane];
            ax += bflo(v0) + bflo(v1) + bflo(v2) + bflo(v3);
            ay += bfhi(v0) + bfhi(v1) + bfhi(v2) + bfhi(v3);
        }
        for (; j < ec; ++j) {
            int nj = __shfl(idx, j);
            uint v = hb[(size_t)nj * 64 + lane];
            ax += bflo(v); ay += bfhi(v);
        }
    }
    gacc[wave][2 * lane]     = ax;
    gacc[wave][2 * lane + 1] = ay;
    __syncthreads();

    if (tid < 128) {
        float s = 0.f;
#pragma unroll
        for (int w = 0; w < 16; ++w) s += gacc[w][tid];
        row[tid] = s;
    }
    __syncthreads();

    float s2 = 0.f;
    if (tid < 128) {
        float s1 = b1[tid];
        for (int k = 0; k < 128; ++k) s1 = fmaf(row[k], W1[k * 128 + tid], s1);
        t1[tid] = fmaxf(s1, 0.f);
    }
    __syncthreads();
    if (tid < 128) {
        s2 = b2[tid];
        for (int k = 0; k < 128; ++k) s2 = fmaf(t1[k], W2[k * 128 + tid], s2);
        red[tid] = s2;
    }
    __syncthreads();
    for (int off = 64; off > 0; off >>= 1) {
        if (tid < off) red[tid] = fmaxf(red[tid], red[tid + off]);
        __syncthreads();
    }
    float m = red[0];
    __syncthreads();
    if (tid < 128) red[tid] = expf(s2 - m);
    __syncthreads();
    for (int off = 64; off > 0; off >>= 1) {
        if (tid < off) red[tid] += red[tid + off];
        __syncthreads();
    }
    if (tid < 128) out[g * 128 + tid] = s2 - (m + logf(red[0]));
}

// ---------------------------------------------------------------------------

extern "C" void kernel_launch(void* const* d_in, const int* in_sizes, int n_in,
                              void* d_out, int out_size, void* d_ws, size_t ws_size,
                              hipStream_t stream) {
    (void)in_sizes; (void)n_in; (void)out_size; (void)ws_size;
    const float* x    = (const float*)d_in[0];
    const int*   ei   = (const int*)d_in[1];
    const int*   n2s  = (const int*)d_in[2];
    const int*   s2g  = (const int*)d_in[3];
    const float* W1a  = (const float*)d_in[4];
    const float* b1a  = (const float*)d_in[5];
    const float* W1b  = (const float*)d_in[6];
    const float* b1b  = (const float*)d_in[7];
    const float* cWa  = (const float*)d_in[8];
    const float* cba  = (const float*)d_in[9];
    const float* cWb  = (const float*)d_in[10];
    const float* cbb  = (const float*)d_in[11];
    const float* l1W  = (const float*)d_in[12];
    const float* l1b  = (const float*)d_in[13];
    const float* l2W  = (const float*)d_in[14];
    const float* l2b  = (const float*)d_in[15];
    float* out = (float*)d_out;

    // workspace layout (~40 MB)
    uint*  hb    = (uint*)d_ws;                          // N*64 (bf16 h)
    uint*  habuf = hb + (size_t)N_NODES * 64;            // N*64 (aggr buf)
    int*   csrcF = (int*)(habuf + (size_t)N_NODES * 64); // N*64 fixed slots
    int*   s2nF  = csrcF + (size_t)N_NODES * 64;         // S*32 fixed slots
    int*   g2sF  = s2nF + SSUB * 32;                     // G*128 fixed slots
    int*   deg   = g2sF + GGRAPH * 128;                  // N   ← memset region
    int*   sdeg  = deg + N_NODES;                        // S
    int*   gcnt  = sdeg + SSUB;                          // G
    ushort* wt   = (ushort*)(gcnt + GGRAPH);             // 7*16384 bf16

    const int* srcA = ei;
    const int* dstA = ei + N_EDGES;
    const int nTileBlocks = (N_NODES + 63) / 64;   // 782

    // --- one memset zeroes deg + sdeg + gcnt (contiguous) ---
    hipMemsetAsync(deg, 0, (size_t)(N_NODES + SSUB + GGRAPH) * 4, stream);

    // --- one prep kernel: edge fill (NT reads) + pool fills + wconv ---
    k_prep<<<PB + NB + SB + WB, 256, 0, stream>>>(srcA, dstA, deg, csrcF,
                                                  n2s, sdeg, s2nF,
                                                  s2g, gcnt, g2sF,
                                                  W1b, cWa, cWb, wt);

    // --- conv 1 (fully fused, parallel gather) -> hb ---
    k_layer1<<<nTileBlocks, 256, 0, stream>>>((const float2*)x, deg, csrcF,
                                              W1a, b1a, wt, b1b, (ushort*)hb);

    // --- convs 2..4: aggr(hb)->habuf, fused MLP(habuf)->hb ---
    for (int i = 0; i < 3; ++i) {
        k_aggr128_bf16<<<N_NODES / 4, 256, 0, stream>>>(hb, deg, csrcF, habuf);
        k_mlp<<<nTileBlocks, 256, 0, stream>>>((const ushort*)habuf,
                                               wt + (size_t)(1 + i) * 16384,
                                               cba + i * HDIM,
                                               wt + (size_t)(4 + i) * 16384,
                                               cbb + i * HDIM,
                                               (ushort*)hb, N_NODES);
    }

    // --- pooling (both levels) + head, one dispatch ---
    k_poolfinal<<<GGRAPH, 1024, 0, stream>>>(hb, sdeg, s2nF, gcnt, g2sF,
                                             l1W, l1b, l2W, l2b, out);
}

// Round 16
// 313.235 us; speedup vs baseline: 1.1830x; 1.0138x over previous
//
#include <hip/hip_runtime.h>
#include <cstddef>

#define N_NODES  50000
#define N_EDGES  800000
#define HDIM     128
#define SSUB     5000
#define GGRAPH   64
#define FILL_Q   416            // blocks per part in edge fill
#define PB       (8 * FILL_Q)   // 3328 edge-fill blocks
#define LDSW     136            // LDS row stride in ushorts (128 + 8 pad)

#define NB 196                  // node blocks ((50000+255)/256)
#define SB 20                   // subgraph blocks ((5000+255)/256)
#define WB 448                  // wconv blocks (7*16384/256)

typedef unsigned int uint;
typedef unsigned short ushort;
typedef __attribute__((ext_vector_type(8))) short bf16x8;
typedef __attribute__((ext_vector_type(16))) float f32x16;

// bf16 helpers (packed pair in a uint: low ushort = even feature, high = odd)
__device__ __forceinline__ float bflo(uint v) { return __uint_as_float(v << 16); }
__device__ __forceinline__ float bfhi(uint v) { return __uint_as_float(v & 0xffff0000u); }
__device__ __forceinline__ uint packbf(float lo, float hi) {
    uint a = __float_as_uint(lo), b = __float_as_uint(hi);
    a = (a + 0x7fff + ((a >> 16) & 1)) >> 16;          // RNE
    b = (b + 0x7fff + ((b >> 16) & 1)) & 0xffff0000u;  // RNE, keep high half
    return a | b;
}
__device__ __forceinline__ ushort bf16of(float f) {
    uint a = __float_as_uint(f);
    a = (a + 0x7fff + ((a >> 16) & 1)) >> 16;
    return (ushort)a;
}

// ---------------------------------------------------------------------------
// One-shot prep:
//  part A (PB blocks): XCD-partitioned fixed-slot edge fill, int4-vectorized
//    dst scan (4 edges/load, 16 B/lane). part=blockIdx&7 owns dst range
//    [part*6250, +6250). Residual ~8x write amplification is temporal
//    eviction — measured invariant to placement/NT/bucketing (R3/R13/R15).
//  part B (NB blocks): fixed-slot subgraph fill (cap 32; actual max ~25).
//  part D (SB blocks): fixed-slot subgraph->graph fill (cap 128; max ~110).
//  part C (WB blocks): weight convert -> bf16 transposed wt[m][n][k]=W[k][n].
// ---------------------------------------------------------------------------

__global__ __launch_bounds__(256) void k_prep(const int* __restrict__ src,
                                              const int* __restrict__ dst,
                                              int* __restrict__ deg,
                                              int* __restrict__ csrcF,
                                              const int* __restrict__ n2s,
                                              int* __restrict__ sdeg,
                                              int* __restrict__ s2nF,
                                              const int* __restrict__ s2g,
                                              int* __restrict__ gcnt,
                                              int* __restrict__ g2sF,
                                              const float* __restrict__ W1b,
                                              const float* __restrict__ cWa,
                                              const float* __restrict__ cWb,
                                              ushort* __restrict__ wt) {
    int b = blockIdx.x, t = threadIdx.x;
    if (b < PB) {
        int part = b & 7;
        int q = b >> 3;
        int lo = part * 6250, hi = lo + 6250;
        for (int e4 = q * 256 + t; e4 < N_EDGES / 4; e4 += FILL_Q * 256) {
            int4 d4 = ((const int4*)dst)[e4];
            int e = e4 * 4;
            if (d4.x >= lo && d4.x < hi) {
                int pos = atomicAdd(&deg[d4.x], 1);
                if (pos < 64) csrcF[(d4.x << 6) + pos] = src[e];
            }
            if (d4.y >= lo && d4.y < hi) {
                int pos = atomicAdd(&deg[d4.y], 1);
                if (pos < 64) csrcF[(d4.y << 6) + pos] = src[e + 1];
            }
            if (d4.z >= lo && d4.z < hi) {
                int pos = atomicAdd(&deg[d4.z], 1);
                if (pos < 64) csrcF[(d4.z << 6) + pos] = src[e + 2];
            }
            if (d4.w >= lo && d4.w < hi) {
                int pos = atomicAdd(&deg[d4.w], 1);
                if (pos < 64) csrcF[(d4.w << 6) + pos] = src[e + 3];
            }
        }
    } else if (b < PB + NB) {
        int i = (b - PB) * 256 + t;
        if (i < N_NODES) {
            int sg = n2s[i];
            int pos = atomicAdd(&sdeg[sg], 1);
            if (pos < 32) s2nF[(sg << 5) + pos] = i;
        }
    } else if (b < PB + NB + SB) {
        int i = (b - PB - NB) * 256 + t;
        if (i < SSUB) {
            int g = s2g[i];
            int pos = atomicAdd(&gcnt[g], 1);
            if (pos < 128) g2sF[(g << 7) + pos] = i;
        }
    } else {
        int gid = (b - PB - NB - SB) * 256 + t;    // 7*16384 total
        int m = gid >> 14, r = gid & 16383;
        int n = r >> 7, k = r & 127;
        const float* Wsrc = (m == 0) ? W1b
                          : (m <= 3) ? cWa + (size_t)(m - 1) * 16384
                                     : cWb + (size_t)(m - 4) * 16384;
        wt[gid] = bf16of(Wsrc[k * 128 + n]);
    }
}

// ---------------------------------------------------------------------------
// Conv 1, fully fused, parallel gather:
//  1a) 4 threads per node gather x (L2-hot) + shfl_xor reduce -> LDS sums
//  1b) wave-per-16-nodes applies W1a+b1a+relu -> 64x128 bf16 LDS tile
//   2) column-sliced 32x32x16 MFMA gemm (W1b^T slice reg-resident) -> hb
// ---------------------------------------------------------------------------

__global__ __launch_bounds__(256) void k_layer1(const float2* __restrict__ x,
                                                const int* __restrict__ deg,
                                                const int* __restrict__ csrcF,
                                                const float* __restrict__ W1a,
                                                const float* __restrict__ b1a,
                                                const ushort* __restrict__ WtA,
                                                const float* __restrict__ bA,
                                                ushort* __restrict__ hbout) {
    __shared__ ushort lds[64 * LDSW];   // 17.4 KB
    __shared__ float2 sums[64];
    const int tid = threadIdx.x, wave = tid >> 6, lane = tid & 63;
    const int nodeBase = blockIdx.x * 64;

    // ---- phase 1a: 4 threads per node gather + reduce ----
    {
        int nl = tid >> 2, sub = tid & 3;
        int gn = nodeBase + nl;
        float tx = 0.f, ty = 0.f;
        if (gn < N_NODES) {
            int e = deg[gn]; if (e > 64) e = 64;
            for (int k = sub; k < e; k += 4) {
                float2 v = x[csrcF[(gn << 6) + k]];
                tx += v.x; ty += v.y;
            }
        }
        tx += __shfl_xor(tx, 1); ty += __shfl_xor(ty, 1);
        tx += __shfl_xor(tx, 2); ty += __shfl_xor(ty, 2);
        if (sub == 0) {
            if (gn < N_NODES) {
                float2 sv = x[gn];
                sums[nl] = make_float2(tx + sv.x, ty + sv.y);
            } else {
                sums[nl] = make_float2(0.f, 0.f);
            }
        }
    }
    __syncthreads();

    // ---- phase 1b: lin1a + relu -> bf16 LDS tile ----
    {
        float2 wlo = ((const float2*)W1a)[lane];        // W1a[0][2l..2l+1]
        float2 whi = ((const float2*)W1a)[64 + lane];   // W1a[1][2l..2l+1]
        float2 bv  = ((const float2*)b1a)[lane];
        for (int n = wave * 16; n < wave * 16 + 16; ++n) {
            float2 ts = sums[n];
            float v0 = fmaf(ts.x, wlo.x, fmaf(ts.y, whi.x, bv.x));
            float v1 = fmaf(ts.x, wlo.y, fmaf(ts.y, whi.y, bv.y));
            *(uint*)(&lds[n * LDSW + 2 * lane]) = packbf(fmaxf(v0, 0.f), fmaxf(v1, 0.f));
        }
    }

    // ---- register-resident WtA slice ----
    const int l32 = lane & 31, hk = lane >> 5;
    const int colBase = wave * 32;
    bf16x8 wa[8];
#pragma unroll
    for (int kk = 0; kk < 8; ++kk)
        wa[kk] = *(const bf16x8*)(WtA + (size_t)(colBase + l32) * 128 + kk * 16 + hk * 8);
    const float biasA = bA[colBase + l32];
    __syncthreads();

    // ---- phase 2: column-sliced gemm, 2 m-tiles of 32 rows ----
    f32x16 acc[2];
#pragma unroll
    for (int m = 0; m < 2; ++m)
#pragma unroll
        for (int r = 0; r < 16; ++r) acc[m][r] = 0.f;
#pragma unroll
    for (int m = 0; m < 2; ++m) {
        const ushort* arow = lds + (m * 32 + l32) * LDSW + hk * 8;
#pragma unroll
        for (int kk = 0; kk < 8; ++kk) {
            bf16x8 a = *(const bf16x8*)(arow + kk * 16);
            acc[m] = __builtin_amdgcn_mfma_f32_32x32x16_bf16(a, wa[kk], acc[m], 0, 0, 0);
        }
    }

    // ---- epilogue: relu(acc + bA) -> bf16 global (masked rows) ----
#pragma unroll
    for (int m = 0; m < 2; ++m) {
#pragma unroll
        for (int r = 0; r < 16; ++r) {
            int rl = (r & 3) + 8 * (r >> 2) + 4 * hk;
            int row = nodeBase + m * 32 + rl;
            if (row < N_NODES)
                hbout[(size_t)row * 128 + colBase + l32] =
                    bf16of(fmaxf(acc[m][r] + biasA, 0.f));
        }
    }
}

// ---------------------------------------------------------------------------
// GIN aggregation, H=128, bf16 in/out: one wave per node, lane holds one uint
// (2 bf16 features), full 256 B row per gather, shfl broadcast of the
// (aligned) fixed-slot csrc list, up to 16 outstanding gathers.
// ---------------------------------------------------------------------------

__global__ __launch_bounds__(256) void k_aggr128_bf16(const uint* __restrict__ hb,
                                                      const int* __restrict__ deg,
                                                      const int* __restrict__ csrcF,
                                                      uint* __restrict__ out) {
    int node = blockIdx.x * 4 + (threadIdx.x >> 6);   // grid = N/4 exact
    int lane = threadIdx.x & 63;
    int cnt = deg[node]; if (cnt > 64) cnt = 64;
    uint sv = hb[(size_t)node * 64 + lane];
    float ax0 = bflo(sv), ay0 = bfhi(sv);
    float ax1 = 0.f, ay1 = 0.f, ax2 = 0.f, ay2 = 0.f, ax3 = 0.f, ay3 = 0.f;
    int idx = csrcF[(node << 6) + ((lane < cnt) ? lane : 0)];   // aligned 256 B load
    int j = 0;
    for (; j + 15 < cnt; j += 16) {                     // 16 outstanding gathers
        int s0 = __shfl(idx, j),      s1 = __shfl(idx, j + 1);
        int s2 = __shfl(idx, j + 2),  s3 = __shfl(idx, j + 3);
        int s4 = __shfl(idx, j + 4),  s5 = __shfl(idx, j + 5);
        int s6 = __shfl(idx, j + 6),  s7 = __shfl(idx, j + 7);
        int s8 = __shfl(idx, j + 8),  s9 = __shfl(idx, j + 9);
        int sa = __shfl(idx, j + 10), sb = __shfl(idx, j + 11);
        int sc = __shfl(idx, j + 12), sd = __shfl(idx, j + 13);
        int se = __shfl(idx, j + 14), sf = __shfl(idx, j + 15);
        uint v0 = hb[(size_t)s0 * 64 + lane];
        uint v1 = hb[(size_t)s1 * 64 + lane];
        uint v2 = hb[(size_t)s2 * 64 + lane];
        uint v3 = hb[(size_t)s3 * 64 + lane];
        uint v4 = hb[(size_t)s4 * 64 + lane];
        uint v5 = hb[(size_t)s5 * 64 + lane];
        uint v6 = hb[(size_t)s6 * 64 + lane];
        uint v7 = hb[(size_t)s7 * 64 + lane];
        uint v8 = hb[(size_t)s8 * 64 + lane];
        uint v9 = hb[(size_t)s9 * 64 + lane];
        uint va = hb[(size_t)sa * 64 + lane];
        uint vb = hb[(size_t)sb * 64 + lane];
        uint vc = hb[(size_t)sc * 64 + lane];
        uint vd = hb[(size_t)sd * 64 + lane];
        uint ve = hb[(size_t)se * 64 + lane];
        uint vf = hb[(size_t)sf * 64 + lane];
        ax0 += bflo(v0); ay0 += bfhi(v0);
        ax1 += bflo(v1); ay1 += bfhi(v1);
        ax2 += bflo(v2); ay2 += bfhi(v2);
        ax3 += bflo(v3); ay3 += bfhi(v3);
        ax0 += bflo(v4); ay0 += bfhi(v4);
        ax1 += bflo(v5); ay1 += bfhi(v5);
        ax2 += bflo(v6); ay2 += bfhi(v6);
        ax3 += bflo(v7); ay3 += bfhi(v7);
        ax0 += bflo(v8); ay0 += bfhi(v8);
        ax1 += bflo(v9); ay1 += bfhi(v9);
        ax2 += bflo(va); ay2 += bfhi(va);
        ax3 += bflo(vb); ay3 += bfhi(vb);
        ax0 += bflo(vc); ay0 += bfhi(vc);
        ax1 += bflo(vd); ay1 += bfhi(vd);
        ax2 += bflo(ve); ay2 += bfhi(ve);
        ax3 += bflo(vf); ay3 += bfhi(vf);
    }
    for (; j + 3 < cnt; j += 4) {
        int s0 = __shfl(idx, j),     s1 = __shfl(idx, j + 1);
        int s2 = __shfl(idx, j + 2), s3 = __shfl(idx, j + 3);
        uint v0 = hb[(size_t)s0 * 64 + lane];
        uint v1 = hb[(size_t)s1 * 64 + lane];
        uint v2 = hb[(size_t)s2 * 64 + lane];
        uint v3 = hb[(size_t)s3 * 64 + lane];
        ax0 += bflo(v0); ay0 += bfhi(v0);
        ax1 += bflo(v1); ay1 += bfhi(v1);
        ax2 += bflo(v2); ay2 += bfhi(v2);
        ax3 += bflo(v3); ay3 += bfhi(v3);
    }
    for (; j < cnt; ++j) {
        int sj = __shfl(idx, j);
        uint v = hb[(size_t)sj * 64 + lane];
        ax0 += bflo(v); ay0 += bfhi(v);
    }
    out[(size_t)node * 64 + lane] =
        packbf((ax0 + ax1) + (ax2 + ax3), (ay0 + ay1) + (ay2 + ay3));
}

// ---------------------------------------------------------------------------
// Fused GIN MLP — R12-proven form: 64-row blocks, column-sliced 32x32x16
// MFMA, B register-resident, coalesced LDS staging of A. Two LDS regions.
// ---------------------------------------------------------------------------

__global__ __launch_bounds__(256) void k_mlp(const ushort* __restrict__ A,
                                             const ushort* __restrict__ WtA,
                                             const float* __restrict__ bA,
                                             const ushort* __restrict__ WtB,
                                             const float* __restrict__ bB,
                                             ushort* __restrict__ C, int nrows) {
    __shared__ ushort ldsA[64 * LDSW];   // input tile (17.4 KB)
    __shared__ ushort ldsB[64 * LDSW];   // intermediate tile (17.4 KB)
    const int tid = threadIdx.x;
    const int wave = tid >> 6, lane = tid & 63;
    const int l32 = lane & 31, hk = lane >> 5;
    const int colBase = wave * 32;
    const int rowBase = blockIdx.x * 64;

    // ---- stage A tile into ldsA (thread t: row t>>2, 64 B quarter) ----
    {
        int r = tid >> 2;
        int qo = (tid & 3) * 32;                    // ushort offset (64 B quarter)
        const uint4* gp = (const uint4*)(A + (size_t)(rowBase + r) * 128 + qo);
        uint4* lp = (uint4*)(ldsA + r * LDSW + qo);
        bool valid = (rowBase + r) < nrows;
#pragma unroll
        for (int q = 0; q < 4; ++q) {
            uint4 v = valid ? gp[q] : (uint4){0u, 0u, 0u, 0u};
            lp[q] = v;
        }
    }

    // ---- register-resident Wt slices (loaded once, L2-hot) ----
    bf16x8 wa[8], wb[8];
#pragma unroll
    for (int kk = 0; kk < 8; ++kk) {
        wa[kk] = *(const bf16x8*)(WtA + (size_t)(colBase + l32) * 128 + kk * 16 + hk * 8);
        wb[kk] = *(const bf16x8*)(WtB + (size_t)(colBase + l32) * 128 + kk * 16 + hk * 8);
    }
    const float biasA = bA[colBase + l32];
    const float biasB = bB[colBase + l32];
    __syncthreads();

    // ---- gemm A (reads ldsA) ----
    f32x16 acc[2];
#pragma unroll
    for (int m = 0; m < 2; ++m)
#pragma unroll
        for (int r = 0; r < 16; ++r) acc[m][r] = 0.f;
#pragma unroll
    for (int m = 0; m < 2; ++m) {
        const ushort* arow = ldsA + (m * 32 + l32) * LDSW + hk * 8;
#pragma unroll
        for (int kk = 0; kk < 8; ++kk) {
            bf16x8 a = *(const bf16x8*)(arow + kk * 16);
            acc[m] = __builtin_amdgcn_mfma_f32_32x32x16_bf16(a, wa[kk], acc[m], 0, 0, 0);
        }
    }

    // ---- relu(acc + bA) -> ldsB ----
#pragma unroll
    for (int m = 0; m < 2; ++m) {
#pragma unroll
        for (int r = 0; r < 16; ++r) {
            int rl = (r & 3) + 8 * (r >> 2) + 4 * hk;
            ldsB[(m * 32 + rl) * LDSW + colBase + l32] =
                bf16of(fmaxf(acc[m][r] + biasA, 0.f));
        }
    }
    __syncthreads();

    // ---- gemm B (reads ldsB) ----
#pragma unroll
    for (int m = 0; m < 2; ++m)
#pragma unroll
        for (int r = 0; r < 16; ++r) acc[m][r] = 0.f;
#pragma unroll
    for (int m = 0; m < 2; ++m) {
        const ushort* arow = ldsB + (m * 32 + l32) * LDSW + hk * 8;
#pragma unroll
        for (int kk = 0; kk < 8; ++kk) {
            bf16x8 a = *(const bf16x8*)(arow + kk * 16);
            acc[m] = __builtin_amdgcn_mfma_f32_32x32x16_bf16(a, wb[kk], acc[m], 0, 0, 0);
        }
    }

    // ---- epilogue: relu(acc + bB) -> bf16 global (masked rows) ----
#pragma unroll
    for (int m = 0; m < 2; ++m) {
#pragma unroll
        for (int r = 0; r < 16; ++r) {
            int rl = (r & 3) + 8 * (r >> 2) + 4 * hk;
            int row = rowBase + m * 32 + rl;
            if (row < nrows)
                C[(size_t)row * 128 + colBase + l32] =
                    bf16of(fmaxf(acc[m][r] + biasB, 0.f));
        }
    }
}

// ---------------------------------------------------------------------------
// Fused pooling + head: one block per graph (1024 threads = 16 waves).
// ---------------------------------------------------------------------------

__global__ __launch_bounds__(1024) void k_poolfinal(const uint* __restrict__ hb,
                                                    const int* __restrict__ sdeg,
                                                    const int* __restrict__ s2nF,
                                                    const int* __restrict__ gcnt,
                                                    const int* __restrict__ g2sF,
                                                    const float* __restrict__ W1,
                                                    const float* __restrict__ b1,
                                                    const float* __restrict__ W2,
                                                    const float* __restrict__ b2,
                                                    float* __restrict__ out) {
    __shared__ float gacc[16][130];   // per-wave accumulators (+pad)
    __shared__ float row[128];
    __shared__ float t1[128];
    __shared__ float red[128];
    const int g = blockIdx.x;
    const int tid = threadIdx.x;
    const int wave = tid >> 6, lane = tid & 63;

    int ns = gcnt[g]; if (ns > 128) ns = 128;
    float ax = 0.f, ay = 0.f;
    for (int si = wave; si < ns; si += 16) {
        int sg = g2sF[(g << 7) + si];
        int ec = sdeg[sg]; if (ec > 32) ec = 32;
        int idx = s2nF[(sg << 5) + ((lane < ec) ? lane : 0)];
        int j = 0;
        for (; j + 3 < ec; j += 4) {
            int n0 = __shfl(idx, j),     n1 = __shfl(idx, j + 1);
            int n2 = __shfl(idx, j + 2), n3 = __shfl(idx, j + 3);
            uint v0 = hb[(size_t)n0 * 64 + lane];
            uint v1 = hb[(size_t)n1 * 64 + lane];
            uint v2 = hb[(size_t)n2 * 64 + lane];
            uint v3 = hb[(size_t)n3 * 64 + lane];
            ax += bflo(v0) + bflo(v1) + bflo(v2) + bflo(v3);
            ay += bfhi(v0) + bfhi(v1) + bfhi(v2) + bfhi(v3);
        }
        for (; j < ec; ++j) {
            int nj = __shfl(idx, j);
            uint v = hb[(size_t)nj * 64 + lane];
            ax += bflo(v); ay += bfhi(v);
        }
    }
    gacc[wave][2 * lane]     = ax;
    gacc[wave][2 * lane + 1] = ay;
    __syncthreads();

    if (tid < 128) {
        float s = 0.f;
#pragma unroll
        for (int w = 0; w < 16; ++w) s += gacc[w][tid];
        row[tid] = s;
    }
    __syncthreads();

    float s2 = 0.f;
    if (tid < 128) {
        float s1 = b1[tid];
        for (int k = 0; k < 128; ++k) s1 = fmaf(row[k], W1[k * 128 + tid], s1);
        t1[tid] = fmaxf(s1, 0.f);
    }
    __syncthreads();
    if (tid < 128) {
        s2 = b2[tid];
        for (int k = 0; k < 128; ++k) s2 = fmaf(t1[k], W2[k * 128 + tid], s2);
        red[tid] = s2;
    }
    __syncthreads();
    for (int off = 64; off > 0; off >>= 1) {
        if (tid < off) red[tid] = fmaxf(red[tid], red[tid + off]);
        __syncthreads();
    }
    float m = red[0];
    __syncthreads();
    if (tid < 128) red[tid] = expf(s2 - m);
    __syncthreads();
    for (int off = 64; off > 0; off >>= 1) {
        if (tid < off) red[tid] += red[tid + off];
        __syncthreads();
    }
    if (tid < 128) out[g * 128 + tid] = s2 - (m + logf(red[0]));
}

// ---------------------------------------------------------------------------

extern "C" void kernel_launch(void* const* d_in, const int* in_sizes, int n_in,
                              void* d_out, int out_size, void* d_ws, size_t ws_size,
                              hipStream_t stream) {
    (void)in_sizes; (void)n_in; (void)out_size; (void)ws_size;
    const float* x    = (const float*)d_in[0];
    const int*   ei   = (const int*)d_in[1];
    const int*   n2s  = (const int*)d_in[2];
    const int*   s2g  = (const int*)d_in[3];
    const float* W1a  = (const float*)d_in[4];
    const float* b1a  = (const float*)d_in[5];
    const float* W1b  = (const float*)d_in[6];
    const float* b1b  = (const float*)d_in[7];
    const float* cWa  = (const float*)d_in[8];
    const float* cba  = (const float*)d_in[9];
    const float* cWb  = (const float*)d_in[10];
    const float* cbb  = (const float*)d_in[11];
    const float* l1W  = (const float*)d_in[12];
    const float* l1b  = (const float*)d_in[13];
    const float* l2W  = (const float*)d_in[14];
    const float* l2b  = (const float*)d_in[15];
    float* out = (float*)d_out;

    // workspace layout (~40 MB)
    uint*  hb    = (uint*)d_ws;                          // N*64 (bf16 h)
    uint*  habuf = hb + (size_t)N_NODES * 64;            // N*64 (aggr buf)
    int*   csrcF = (int*)(habuf + (size_t)N_NODES * 64); // N*64 fixed slots
    int*   s2nF  = csrcF + (size_t)N_NODES * 64;         // S*32 fixed slots
    int*   g2sF  = s2nF + SSUB * 32;                     // G*128 fixed slots
    int*   deg   = g2sF + GGRAPH * 128;                  // N   ← memset region
    int*   sdeg  = deg + N_NODES;                        // S
    int*   gcnt  = sdeg + SSUB;                          // G
    ushort* wt   = (ushort*)(gcnt + GGRAPH);             // 7*16384 bf16

    const int* srcA = ei;
    const int* dstA = ei + N_EDGES;
    const int nTileBlocks = (N_NODES + 63) / 64;   // 782

    // --- one memset zeroes deg + sdeg + gcnt (contiguous) ---
    hipMemsetAsync(deg, 0, (size_t)(N_NODES + SSUB + GGRAPH) * 4, stream);

    // --- one prep kernel: edge fill (int4 scan) + pool fills + wconv ---
    k_prep<<<PB + NB + SB + WB, 256, 0, stream>>>(srcA, dstA, deg, csrcF,
                                                  n2s, sdeg, s2nF,
                                                  s2g, gcnt, g2sF,
                                                  W1b, cWa, cWb, wt);

    // --- conv 1 (fully fused, parallel gather) -> hb ---
    k_layer1<<<nTileBlocks, 256, 0, stream>>>((const float2*)x, deg, csrcF,
                                              W1a, b1a, wt, b1b, (ushort*)hb);

    // --- convs 2..4: aggr(hb)->habuf, fused MLP(habuf)->hb ---
    for (int i = 0; i < 3; ++i) {
        k_aggr128_bf16<<<N_NODES / 4, 256, 0, stream>>>(hb, deg, csrcF, habuf);
        k_mlp<<<nTileBlocks, 256, 0, stream>>>((const ushort*)habuf,
                                               wt + (size_t)(1 + i) * 16384,
                                               cba + i * HDIM,
                                               wt + (size_t)(4 + i) * 16384,
                                               cbb + i * HDIM,
                                               (ushort*)hb, N_NODES);
    }

    // --- pooling (both levels) + head, one dispatch ---
    k_poolfinal<<<GGRAPH, 1024, 0, stream>>>(hb, sdeg, s2nF, gcnt, g2sF,
                                             l1W, l1b, l2W, l2b, out);
}